// Round 11
// baseline (144.965 us; speedup 1.0000x reference)
//
#include <hip/hip_runtime.h>
#include <math.h>

#define B_ 2
#define H_ 96
#define W_ 96
#define L_ (H_*W_)        // 9216
#define BL_ (B_*L_)       // 18432
#define DM_ 128
#define DI_ 256
#define DS_ 16
#define DR_ 8
#define C_ 384            // chunks per sequence
#define CL_ (L_/C_)       // 24 steps per chunk
#define G_ 16             // chunk groups per sequence
#define GC_ (C_/G_)       // 24 chunks per group
#define GP_ 264           // padded gls row stride (ushorts): 528B -> 4-bank row rotation

typedef __attribute__((ext_vector_type(8))) short short8;   // 8 bf16 in 4 VGPRs
typedef __attribute__((ext_vector_type(4))) float f32x4;    // MFMA accumulator

static __device__ __forceinline__ unsigned short f2bf(float f) {
  unsigned int u = __float_as_uint(f);
  unsigned int r = (u + 0x7fffu + ((u >> 16) & 1u)) >> 16;  // RNE
  return (unsigned short)r;
}
static __device__ __forceinline__ float bf2f(unsigned short u) {
  return __uint_as_float(((unsigned int)u) << 16);
}

// ---------------- Weight prep (packed bf16 fragment panels) + x->bf16 ----------------
__global__ __launch_bounds__(256) void k_wprep(const float* __restrict__ xpw,
                                               const float* __restrict__ dtw,
                                               const float* __restrict__ ipw,
                                               const float* __restrict__ opw,
                                               const float* __restrict__ x,
                                               unsigned short* __restrict__ wallp,
                                               unsigned short* __restrict__ w2p,
                                               unsigned short* __restrict__ wop,
                                               unsigned short* __restrict__ xbf) {
  int bid = blockIdx.x, tid = threadIdx.x;
  if (bid < 288) {                       // Wall: 288 x 256 (K=256, 8 ks, 18 tiles)
    int n = bid, k = tid;
    float v;
    if (n < 256) {
      float s = 0.f;
#pragma unroll
      for (int r = 0; r < DR_; r++) s += xpw[r * DI_ + k] * dtw[n * DR_ + r];
      v = s;
    } else {
      v = xpw[(n - 248) * DI_ + k];      // B rows (8..23) and C rows (24..39)
    }
    int t = n >> 4, col = n & 15, ks = k >> 5, kk = k & 31;
    int lane = (kk >> 3) * 16 + col, i = kk & 7;
    wallp[(((ks * 18 + t) * 64 + lane) << 3) + i] = f2bf(v);
  } else if (bid < 544) {                // in_proj: 512 x 128 (K=128, 4 ks, 32 tiles)
    int n = (bid - 288) * 2 + (tid >> 7), k = tid & 127;
    int t = n >> 4, col = n & 15, ks = k >> 5, kk = k & 31;
    int lane = (kk >> 3) * 16 + col, i = kk & 7;
    w2p[(((ks * 32 + t) * 64 + lane) << 3) + i] = f2bf(ipw[n * DM_ + k]);
  } else if (bid < 672) {                // out_proj: 128 x 256 (K=256, 8 ks, 8 tiles)
    int n = bid - 544, k = tid;
    int t = n >> 4, col = n & 15, ks = k >> 5, kk = k & 31;
    int lane = (kk >> 3) * 16 + col, i = kk & 7;
    wop[(((ks * 8 + t) * 64 + lane) << 3) + i] = f2bf(opw[n * DI_ + k]);
  } else {                               // x -> bf16
    int i = ((bid - 672) * 256 + tid) * 8;
    float4 f0 = *(const float4*)(x + i);
    float4 f1 = *(const float4*)(x + i + 4);
    short8 o;
    o[0]=(short)f2bf(f0.x); o[1]=(short)f2bf(f0.y); o[2]=(short)f2bf(f0.z); o[3]=(short)f2bf(f0.w);
    o[4]=(short)f2bf(f1.x); o[5]=(short)f2bf(f1.y); o[6]=(short)f2bf(f1.z); o[7]=(short)f2bf(f1.w);
    *(short8*)(xbf + i) = o;
  }
}

// ---------------- in_proj MFMA: (BL,128)x(128,512) -> xi bf16 | z bf16, col-split x4 ----------------
__global__ __launch_bounds__(256) void k_in_mfma(const unsigned short* __restrict__ xbf,
                                                 const unsigned short* __restrict__ w2p,
                                                 unsigned short* __restrict__ xi_bf,
                                                 unsigned short* __restrict__ zb) {
  int wid = threadIdx.x >> 6, lane = threadIdx.x & 63;
  int m0 = blockIdx.x * 64 + wid * 16;
  int t0 = blockIdx.y * 8;
  int row = m0 + (lane & 15);
  int col = lane & 15, r4 = (lane >> 4) * 4;
  f32x4 acc[8];
#pragma unroll
  for (int j = 0; j < 8; j++) acc[j] = (f32x4){0.f, 0.f, 0.f, 0.f};
#pragma unroll
  for (int ks = 0; ks < 4; ks++) {
    short8 a = *(const short8*)(xbf + (size_t)row * DM_ + ks * 32 + (lane >> 4) * 8);
#pragma unroll
    for (int j = 0; j < 8; j++) {
      short8 b = *(const short8*)(w2p + (((ks * 32 + t0 + j) * 64 + lane) << 3));
      acc[j] = __builtin_amdgcn_mfma_f32_16x16x32_bf16(a, b, acc[j], 0, 0, 0);
    }
  }
#pragma unroll
  for (int j = 0; j < 8; j++) {
    int tg = t0 + j;
    if (tg < 16) {
#pragma unroll
      for (int q = 0; q < 4; q++)
        xi_bf[(size_t)(m0 + r4 + q) * DI_ + tg * 16 + col] = f2bf(acc[j][q]);
    } else {
#pragma unroll
      for (int q = 0; q < 4; q++)
        zb[(size_t)(m0 + r4 + q) * DI_ + (tg - 16) * 16 + col] = f2bf(acc[j][q]);
    }
  }
}

// ---------------- depthwise 3x3 conv + bias + SiLU (bf16 in) -> xs bf16 ----------------
__global__ __launch_bounds__(256) void k_conv(const unsigned short* __restrict__ xi_bf,
                                              const float* __restrict__ cw,
                                              const float* __restrict__ cb,
                                              unsigned short* __restrict__ xs_bf) {
  int wt = blockIdx.x;        // 0..5
  int h  = blockIdx.y;        // 0..95
  int b  = blockIdx.z;        // 0..1
  int d  = threadIdx.x;       // channel
  int w0 = wt * 16;
  float wgt[9];
#pragma unroll
  for (int k = 0; k < 9; k++) wgt[k] = cw[d * 9 + k];
  float bias = cb[d];

  float v[3][18];
#pragma unroll
  for (int r = 0; r < 3; r++) {
    int hh = h - 1 + r;
    bool rok = (hh >= 0) & (hh < H_);
    const unsigned short* rowp = xi_bf + ((size_t)(b * H_ + hh) * W_) * DI_ + d;
#pragma unroll
    for (int j = 0; j < 18; j++) {
      int ww = w0 - 1 + j;
      bool ok = rok & (ww >= 0) & (ww < W_);
      v[r][j] = ok ? bf2f(rowp[(size_t)ww * DI_]) : 0.f;   // block-uniform predicate
    }
  }
#pragma unroll
  for (int j = 0; j < 16; j++) {
    float acc = bias;
#pragma unroll
    for (int r = 0; r < 3; r++)
#pragma unroll
      for (int q = 0; q < 3; q++)
        acc = fmaf(v[r][j + q], wgt[r * 3 + q], acc);
    float sg = 1.0f / (1.0f + __expf(-acc));
    float o = acc * sg;
    size_t bl = (size_t)(b * H_ + h) * W_ + w0 + j;
    xs_bf[bl * DI_ + d] = f2bf(o);
  }
}

// ---------------- x-side MFMA: (BL,256)x(256,288), col-split x3 ----------------
__global__ __launch_bounds__(256) void k_xmfma(const unsigned short* __restrict__ xs_bf,
                                               const unsigned short* __restrict__ wallp,
                                               const float* __restrict__ dtb,
                                               float* __restrict__ delta,
                                               float* __restrict__ Bsb,
                                               float* __restrict__ Csb) {
  int wid = threadIdx.x >> 6, lane = threadIdx.x & 63;
  int m0 = blockIdx.x * 64 + wid * 16;
  int t0 = blockIdx.y * 6;
  int row = m0 + (lane & 15);
  int col = lane & 15, r4 = (lane >> 4) * 4;
  f32x4 acc[6];
#pragma unroll
  for (int j = 0; j < 6; j++) acc[j] = (f32x4){0.f, 0.f, 0.f, 0.f};
#pragma unroll
  for (int ks = 0; ks < 8; ks++) {
    short8 a = *(const short8*)(xs_bf + (size_t)row * DI_ + ks * 32 + (lane >> 4) * 8);
#pragma unroll
    for (int j = 0; j < 6; j++) {
      short8 b = *(const short8*)(wallp + (((ks * 18 + t0 + j) * 64 + lane) << 3));
      acc[j] = __builtin_amdgcn_mfma_f32_16x16x32_bf16(a, b, acc[j], 0, 0, 0);
    }
  }
#pragma unroll
  for (int j = 0; j < 6; j++) {
    int t = t0 + j;
    if (t < 16) {
      float bias = dtb[t * 16 + col];
#pragma unroll
      for (int q = 0; q < 4; q++) {
        float v = acc[j][q] + bias;
        float sp = (v > 20.f) ? v : log1pf(__expf(v));
        delta[(size_t)(m0 + r4 + q) * DI_ + t * 16 + col] = sp;
      }
    } else if (t == 16) {
#pragma unroll
      for (int q = 0; q < 4; q++)
        Bsb[(size_t)(m0 + r4 + q) * DS_ + col] = acc[j][q];
    } else {
#pragma unroll
      for (int q = 0; q < 4; q++)
        Csb[(size_t)(m0 + r4 + q) * DS_ + col] = acc[j][q];
    }
  }
}

// ---------------- Scan pass 1: register-batched chunk scan, B staged in LDS ----------------
__global__ __launch_bounds__(256, 3) void k_scan1(const float* __restrict__ delta,
                                                  const unsigned short* __restrict__ xs_bf,
                                                  const float* __restrict__ Bsb,
                                                  const float* __restrict__ A_logs,
                                                  float* __restrict__ S_buf,
                                                  float* __restrict__ sumD_buf) {
  int c = blockIdx.x, b = blockIdx.y;
  int d = threadIdx.x;
  __shared__ float sB[CL_][DS_];
  size_t base = (size_t)b * L_ + (size_t)c * CL_;
  for (int i = d; i < CL_ * DS_; i += 256)
    sB[i >> 4][i & 15] = Bsb[base * DS_ + i];
  float a2[DS_];
#pragma unroll
  for (int n = 0; n < DS_; n++)
    a2[n] = -__expf(A_logs[d * DS_ + n]) * 1.44269504f;
  float dvA[CL_], xvA[CL_];
#pragma unroll
  for (int s = 0; s < CL_; s++) {
    dvA[s] = delta[(base + s) * DI_ + d];
    xvA[s] = bf2f(xs_bf[(base + s) * DI_ + d]);
  }
  __syncthreads();
  float h[DS_];
#pragma unroll
  for (int n = 0; n < DS_; n++) h[n] = 0.f;
  float sum = 0.f;
#pragma unroll
  for (int s = 0; s < CL_; s++) {
    float4 b0 = *(const float4*)&sB[s][0];
    float4 b1 = *(const float4*)&sB[s][4];
    float4 b2 = *(const float4*)&sB[s][8];
    float4 b3 = *(const float4*)&sB[s][12];
    float Bv[DS_] = {b0.x,b0.y,b0.z,b0.w, b1.x,b1.y,b1.z,b1.w,
                     b2.x,b2.y,b2.z,b2.w, b3.x,b3.y,b3.z,b3.w};
    float dv = dvA[s];
    float dvx = dv * xvA[s];
    sum += dv;
#pragma unroll
    for (int n = 0; n < DS_; n++)
      h[n] = fmaf(exp2f(dv * a2[n]), h[n], dvx * Bv[n]);
  }
  size_t o = ((size_t)(b * C_ + c) * DI_ + d) * DS_;
#pragma unroll
  for (int q = 0; q < 4; q++)
    *(float4*)(S_buf + o + 4 * q) = (float4){h[4*q], h[4*q+1], h[4*q+2], h[4*q+3]};
  sumD_buf[(size_t)(b * C_ + c) * DI_ + d] = sum;
}

// ---------------- Scan pass 2a: group-local chunk prefix (prefetched) ----------------
__global__ __launch_bounds__(256) void k_scan2a(const float* __restrict__ S_buf,
                                                float* __restrict__ sumD_csd,
                                                const float* __restrict__ A_logs,
                                                float* __restrict__ hin_loc,
                                                float* __restrict__ HgS,
                                                float* __restrict__ gsd) {
  int t = blockIdx.x * 256 + threadIdx.x;   // 0 .. B*G*DI*DS-1
  int b = t >> 16;
  int g = (t >> 12) & 15;
  int d = (t >> 4) & 255;
  int n = t & 15;
  float a2 = -__expf(A_logs[d * DS_ + n]) * 1.44269504f;
  float h = 0.f, csd = 0.f;
  int c0 = b * C_ + g * GC_;
  const size_t stride = (size_t)DI_ * DS_;
  size_t o  = ((size_t)c0 * DI_ + d) * DS_ + n;
  size_t od = (size_t)c0 * DI_ + d;
  float S  = S_buf[o];
  float sd = sumD_csd[od];
#pragma unroll
  for (int j = 0; j < GC_; j++) {
    float Sn = 0.f, sdn = 0.f;
    if (j + 1 < GC_) {
      Sn  = S_buf[o + stride];
      sdn = sumD_csd[od + DI_];
    }
    hin_loc[o] = h;
    if (n == 0) sumD_csd[od] = csd;
    csd += sd;
    h = fmaf(exp2f(a2 * sd), h, S);
    S = Sn; sd = sdn;
    o += stride; od += DI_;
  }
  size_t og = ((size_t)(b * G_ + g) * DI_ + d) * DS_ + n;
  HgS[og] = h;
  if (n == 0) gsd[(size_t)(b * G_ + g) * DI_ + d] = csd;
}

// ---------------- Scan pass 2b: combine group summaries ----------------
__global__ __launch_bounds__(256) void k_scan2b(float* __restrict__ HgS_Hpre,
                                                const float* __restrict__ gsd,
                                                const float* __restrict__ A_logs) {
  int t = blockIdx.x * 256 + threadIdx.x;   // 0 .. 8191
  int b = t >> 12;
  int d = (t >> 4) & 255;
  int n = t & 15;
  float a2 = -__expf(A_logs[d * DS_ + n]) * 1.44269504f;
  float h = 0.f;
#pragma unroll
  for (int g = 0; g < G_; g++) {
    size_t o = ((size_t)(b * G_ + g) * DI_ + d) * DS_ + n;
    float Hg = HgS_Hpre[o];
    float sd = gsd[(size_t)(b * G_ + g) * DI_ + d];
    HgS_Hpre[o] = h;
    h = fmaf(exp2f(a2 * sd), h, Hg);
  }
}

// ---------------- Scan pass 3 + LN + SiLU(z) gate + fused out_proj MFMA -> out ----------------
__global__ __launch_bounds__(256, 3) void k_scan3(const float* __restrict__ delta,
                                                   const unsigned short* __restrict__ xs_bf,
                                                   const float* __restrict__ Bsb,
                                                   const float* __restrict__ Csb,
                                                   const float* __restrict__ A_logs,
                                                   const float* __restrict__ Ds,
                                                   const float* __restrict__ hin_loc,
                                                   const float* __restrict__ Hpre,
                                                   const float* __restrict__ csd,
                                                   const unsigned short* __restrict__ zb,
                                                   const float* __restrict__ lng,
                                                   const float* __restrict__ lnb,
                                                   const unsigned short* __restrict__ wop,
                                                   float* __restrict__ out) {
  int c = blockIdx.x, b = blockIdx.y;
  int d = threadIdx.x;
  int grp = c / GC_;
  __shared__ float ysm[CL_][DI_];
  __shared__ unsigned short gls[32][GP_];   // g tile, padded stride (rows 24..31 unused)
  __shared__ float sBC[2][CL_][DS_];
  __shared__ float smu[CL_], srs[CL_];
  size_t base = (size_t)b * L_ + (size_t)c * CL_;
  for (int i = d; i < CL_ * DS_; i += 256) {
    sBC[0][i >> 4][i & 15] = Bsb[base * DS_ + i];
    sBC[1][i >> 4][i & 15] = Csb[base * DS_ + i];
  }
  float a2[DS_];
#pragma unroll
  for (int n = 0; n < DS_; n++)
    a2[n] = -__expf(A_logs[d * DS_ + n]) * 1.44269504f;
  float Dv = Ds[d];
  float dvA[CL_], xvA[CL_];
#pragma unroll
  for (int s = 0; s < CL_; s++) {
    dvA[s] = delta[(base + s) * DI_ + d];
    xvA[s] = bf2f(xs_bf[(base + s) * DI_ + d]);
  }
  // seed: h = hin_loc + exp2(a2*csd) * Hpre[grp]
  float h[DS_];
  {
    size_t ho = ((size_t)(b * C_ + c) * DI_ + d) * DS_;
    size_t go = ((size_t)(b * G_ + grp) * DI_ + d) * DS_;
    float cs = csd[(size_t)(b * C_ + c) * DI_ + d];
#pragma unroll
    for (int q = 0; q < 4; q++) {
      float4 tl = *(const float4*)(hin_loc + ho + 4 * q);
      float4 tp = *(const float4*)(Hpre + go + 4 * q);
      h[4*q+0] = fmaf(exp2f(cs * a2[4*q+0]), tp.x, tl.x);
      h[4*q+1] = fmaf(exp2f(cs * a2[4*q+1]), tp.y, tl.y);
      h[4*q+2] = fmaf(exp2f(cs * a2[4*q+2]), tp.z, tl.z);
      h[4*q+3] = fmaf(exp2f(cs * a2[4*q+3]), tp.w, tl.w);
    }
  }
  __syncthreads();
#pragma unroll
  for (int s = 0; s < CL_; s++) {
    float4 b0 = *(const float4*)&sBC[0][s][0];
    float4 b1 = *(const float4*)&sBC[0][s][4];
    float4 b2 = *(const float4*)&sBC[0][s][8];
    float4 b3 = *(const float4*)&sBC[0][s][12];
    float4 c0 = *(const float4*)&sBC[1][s][0];
    float4 c1 = *(const float4*)&sBC[1][s][4];
    float4 c2 = *(const float4*)&sBC[1][s][8];
    float4 c3 = *(const float4*)&sBC[1][s][12];
    float Bv[DS_] = {b0.x,b0.y,b0.z,b0.w, b1.x,b1.y,b1.z,b1.w,
                     b2.x,b2.y,b2.z,b2.w, b3.x,b3.y,b3.z,b3.w};
    float Cv[DS_] = {c0.x,c0.y,c0.z,c0.w, c1.x,c1.y,c1.z,c1.w,
                     c2.x,c2.y,c2.z,c2.w, c3.x,c3.y,c3.z,c3.w};
    float dv = dvA[s], xv = xvA[s];
    float dvx = dv * xv;
    float y0 = Dv * xv, y1 = 0.f, y2 = 0.f, y3 = 0.f;
#pragma unroll
    for (int k = 0; k < 4; k++) {
      int n0 = k, n1_ = 4 + k, n2 = 8 + k, n3 = 12 + k;
      h[n0] = fmaf(exp2f(dv * a2[n0]), h[n0], dvx * Bv[n0]);
      y0 = fmaf(h[n0], Cv[n0], y0);
      h[n1_] = fmaf(exp2f(dv * a2[n1_]), h[n1_], dvx * Bv[n1_]);
      y1 = fmaf(h[n1_], Cv[n1_], y1);
      h[n2] = fmaf(exp2f(dv * a2[n2]), h[n2], dvx * Bv[n2]);
      y2 = fmaf(h[n2], Cv[n2], y2);
      h[n3] = fmaf(exp2f(dv * a2[n3]), h[n3], dvx * Bv[n3]);
      y3 = fmaf(h[n3], Cv[n3], y3);
    }
    ysm[s][d] = (y0 + y1) + (y2 + y3);
  }
  __syncthreads();
  {
    int wid = d >> 6, lane = d & 63;
#pragma unroll
    for (int s6 = 0; s6 < CL_ / 4; s6++) {
      int s = wid * (CL_ / 4) + s6;
      float p0 = ysm[s][lane], p1 = ysm[s][lane + 64];
      float p2 = ysm[s][lane + 128], p3 = ysm[s][lane + 192];
      float s1 = (p0 + p1) + (p2 + p3);
      float s2 = (p0*p0 + p1*p1) + (p2*p2 + p3*p3);
#pragma unroll
      for (int off = 32; off >= 1; off >>= 1) {
        s1 += __shfl_xor(s1, off);
        s2 += __shfl_xor(s2, off);
      }
      if (lane == 0) {
        float mu = s1 / DI_;
        smu[s] = mu;
        srs[s] = rsqrtf(s2 / DI_ - mu * mu + 1e-5f);
      }
    }
  }
  __syncthreads();
  float lg = lng[d], lb = lnb[d];
#pragma unroll
  for (int s = 0; s < CL_; s++) {
    float v = (ysm[s][d] - smu[s]) * srs[s] * lg + lb;
    float zz = bf2f(zb[(base + s) * DI_ + d]);
    float sg = zz / (1.f + __expf(-zz));
    gls[s][d] = f2bf(v * sg);
  }
  __syncthreads();
  // ---- fused out_proj: (24x256) @ (256x128)^T via MFMA; 4 waves x (2 M-tiles x 2 N-tiles)
  {
    int wid = d >> 6, lane = d & 63;
    int colp = lane & 15, r4p = (lane >> 4) * 4;
    int k0 = (lane >> 4) * 8;
    f32x4 oacc[2][2];
#pragma unroll
    for (int mt = 0; mt < 2; mt++)
#pragma unroll
      for (int j = 0; j < 2; j++) oacc[mt][j] = (f32x4){0.f, 0.f, 0.f, 0.f};
#pragma unroll
    for (int ks = 0; ks < 8; ks++) {
      short8 a0 = *(const short8*)&gls[lane & 15][ks * 32 + k0];
      short8 a1 = *(const short8*)&gls[16 + (lane & 15)][ks * 32 + k0];
#pragma unroll
      for (int j = 0; j < 2; j++) {
        int nt = wid * 2 + j;
        short8 bfr = *(const short8*)(wop + (((ks * 8 + nt) * 64 + lane) << 3));
        oacc[0][j] = __builtin_amdgcn_mfma_f32_16x16x32_bf16(a0, bfr, oacc[0][j], 0, 0, 0);
        oacc[1][j] = __builtin_amdgcn_mfma_f32_16x16x32_bf16(a1, bfr, oacc[1][j], 0, 0, 0);
      }
    }
#pragma unroll
    for (int mt = 0; mt < 2; mt++)
#pragma unroll
      for (int j = 0; j < 2; j++) {
        int nt = wid * 2 + j;
#pragma unroll
        for (int q = 0; q < 4; q++) {
          int rl = mt * 16 + r4p + q;
          if (rl < CL_)
            out[(base + rl) * DM_ + nt * 16 + colp] = oacc[mt][j][q];
        }
      }
  }
}

extern "C" void kernel_launch(void* const* d_in, const int* in_sizes, int n_in,
                              void* d_out, int out_size, void* d_ws, size_t ws_size,
                              hipStream_t stream) {
  const float* x         = (const float*)d_in[0];
  const float* in_proj_w = (const float*)d_in[1];
  const float* conv_w    = (const float*)d_in[2];
  const float* conv_b    = (const float*)d_in[3];
  const float* x_proj_w  = (const float*)d_in[4];
  const float* dt_w      = (const float*)d_in[5];
  const float* dt_b      = (const float*)d_in[6];
  const float* A_logs    = (const float*)d_in[7];
  const float* Ds        = (const float*)d_in[8];
  const float* ln_g      = (const float*)d_in[9];
  const float* ln_b      = (const float*)d_in[10];
  const float* out_proj_w= (const float*)d_in[11];
  float* out = (float*)d_out;

  float* ws = (float*)d_ws;
  size_t n1 = (size_t)BL_ * DI_;
  // slot 0: xi bf16 -> S_buf fp32 (xi dead after conv; S_buf written by scan1)
  unsigned short* xi_bf = (unsigned short*)ws;
  float* S_buf  = ws;
  // slot 1: z bf16 + xs bf16
  unsigned short* z_bf  = (unsigned short*)(ws + n1);
  unsigned short* xs_bf = z_bf + n1;
  // slot 3: delta fp32
  float* delta  = ws + 3 * n1;
  float* Bsb    = ws + 4 * n1;
  float* Csb    = Bsb + (size_t)BL_ * DS_;
  float* hin_loc= Csb + (size_t)BL_ * DS_;                       // B*C*DI*DS = 12.6 MB
  float* sumD   = hin_loc + (size_t)B_ * C_ * DI_ * DS_;
  float* HgS    = sumD + (size_t)B_ * C_ * DI_;
  float* gsd    = HgS + (size_t)B_ * G_ * DI_ * DS_;
  unsigned short* wallp = (unsigned short*)(gsd + (size_t)B_ * G_ * DI_);
  unsigned short* w2p   = wallp + 288 * DI_;
  unsigned short* wop   = w2p + 512 * DM_;
  unsigned short* x_bf  = (unsigned short*)hin_loc;  // scratch; dead before scan2a writes

  k_wprep<<<672 + (BL_ * DM_) / 2048, 256, 0, stream>>>(x_proj_w, dt_w, in_proj_w, out_proj_w, x,
                                                        wallp, w2p, wop, x_bf);
  k_in_mfma<<<dim3(BL_ / 64, 4), 256, 0, stream>>>(x_bf, w2p, xi_bf, z_bf);
  k_conv<<<dim3(W_ / 16, H_, B_), 256, 0, stream>>>(xi_bf, conv_w, conv_b, xs_bf);
  k_xmfma<<<dim3(BL_ / 64, 3), 256, 0, stream>>>(xs_bf, wallp, dt_b, delta, Bsb, Csb);
  k_scan1<<<dim3(C_, B_), 256, 0, stream>>>(delta, xs_bf, Bsb, A_logs, S_buf, sumD);
  k_scan2a<<<(B_ * G_ * DI_ * DS_) / 256, 256, 0, stream>>>(S_buf, sumD, A_logs, hin_loc, HgS, gsd);
  k_scan2b<<<(B_ * DI_ * DS_) / 256, 256, 0, stream>>>(HgS, gsd, A_logs);
  k_scan3<<<dim3(C_, B_), 256, 0, stream>>>(delta, xs_bf, Bsb, Csb, A_logs, Ds, hin_loc, HgS, sumD,
                                            z_bf, ln_g, ln_b, wop, out);
}

// Round 12
// 123.307 us; speedup vs baseline: 1.1756x; 1.1756x over previous
//
#include <hip/hip_runtime.h>
#include <math.h>

#define B_ 2
#define H_ 96
#define W_ 96
#define L_ (H_*W_)        // 9216
#define BL_ (B_*L_)       // 18432
#define DM_ 128
#define DI_ 256
#define DS_ 16
#define DR_ 8
#define C_ 384            // chunks per sequence
#define CL_ (L_/C_)       // 24 steps per chunk
#define G_ 16             // chunk groups per sequence
#define GC_ (C_/G_)       // 24 chunks per group
#define GP_ 264           // padded gls row stride (ushorts)

typedef __attribute__((ext_vector_type(8))) short short8;   // 8 bf16 in 4 VGPRs
typedef __attribute__((ext_vector_type(4))) float f32x4;    // MFMA accumulator

static __device__ __forceinline__ unsigned short f2bf(float f) {
  unsigned int u = __float_as_uint(f);
  unsigned int r = (u + 0x7fffu + ((u >> 16) & 1u)) >> 16;  // RNE
  return (unsigned short)r;
}
static __device__ __forceinline__ float bf2f(unsigned short u) {
  return __uint_as_float(((unsigned int)u) << 16);
}

// p^(k+1) for k=0..15 via binary tree (depth 4, 15 muls)
#define POW_TREE(p, pw) \
  pw[0]=(p); pw[1]=pw[0]*pw[0]; pw[2]=pw[1]*pw[0]; pw[3]=pw[1]*pw[1]; \
  pw[4]=pw[3]*pw[0]; pw[5]=pw[3]*pw[1]; pw[6]=pw[3]*pw[2]; pw[7]=pw[3]*pw[3]; \
  pw[8]=pw[7]*pw[0]; pw[9]=pw[7]*pw[1]; pw[10]=pw[7]*pw[2]; pw[11]=pw[7]*pw[3]; \
  pw[12]=pw[7]*pw[4]; pw[13]=pw[7]*pw[5]; pw[14]=pw[7]*pw[6]; pw[15]=pw[7]*pw[7];

// ---------------- Weight prep (packed bf16 fragment panels) + x->bf16 ----------------
__global__ __launch_bounds__(256) void k_wprep(const float* __restrict__ xpw,
                                               const float* __restrict__ dtw,
                                               const float* __restrict__ ipw,
                                               const float* __restrict__ opw,
                                               const float* __restrict__ x,
                                               unsigned short* __restrict__ wallp,
                                               unsigned short* __restrict__ w2p,
                                               unsigned short* __restrict__ wop,
                                               unsigned short* __restrict__ xbf) {
  int bid = blockIdx.x, tid = threadIdx.x;
  if (bid < 288) {                       // Wall: 288 x 256 (K=256, 8 ks, 18 tiles)
    int n = bid, k = tid;
    float v;
    if (n < 256) {
      float s = 0.f;
#pragma unroll
      for (int r = 0; r < DR_; r++) s += xpw[r * DI_ + k] * dtw[n * DR_ + r];
      v = s;
    } else {
      v = xpw[(n - 248) * DI_ + k];      // B rows (8..23) and C rows (24..39)
    }
    int t = n >> 4, col = n & 15, ks = k >> 5, kk = k & 31;
    int lane = (kk >> 3) * 16 + col, i = kk & 7;
    wallp[(((ks * 18 + t) * 64 + lane) << 3) + i] = f2bf(v);
  } else if (bid < 544) {                // in_proj: 512 x 128 (K=128, 4 ks, 32 tiles)
    int n = (bid - 288) * 2 + (tid >> 7), k = tid & 127;
    int t = n >> 4, col = n & 15, ks = k >> 5, kk = k & 31;
    int lane = (kk >> 3) * 16 + col, i = kk & 7;
    w2p[(((ks * 32 + t) * 64 + lane) << 3) + i] = f2bf(ipw[n * DM_ + k]);
  } else if (bid < 672) {                // out_proj: 128 x 256 (K=256, 8 ks, 8 tiles)
    int n = bid - 544, k = tid;
    int t = n >> 4, col = n & 15, ks = k >> 5, kk = k & 31;
    int lane = (kk >> 3) * 16 + col, i = kk & 7;
    wop[(((ks * 8 + t) * 64 + lane) << 3) + i] = f2bf(opw[n * DI_ + k]);
  } else {                               // x -> bf16
    int i = ((bid - 672) * 256 + tid) * 8;
    float4 f0 = *(const float4*)(x + i);
    float4 f1 = *(const float4*)(x + i + 4);
    short8 o;
    o[0]=(short)f2bf(f0.x); o[1]=(short)f2bf(f0.y); o[2]=(short)f2bf(f0.z); o[3]=(short)f2bf(f0.w);
    o[4]=(short)f2bf(f1.x); o[5]=(short)f2bf(f1.y); o[6]=(short)f2bf(f1.z); o[7]=(short)f2bf(f1.w);
    *(short8*)(xbf + i) = o;
  }
}

// ---------------- in_proj MFMA: (BL,128)x(128,512) -> xi bf16 | z bf16, col-split x4 ----------------
__global__ __launch_bounds__(256) void k_in_mfma(const unsigned short* __restrict__ xbf,
                                                 const unsigned short* __restrict__ w2p,
                                                 unsigned short* __restrict__ xi_bf,
                                                 unsigned short* __restrict__ zb) {
  int wid = threadIdx.x >> 6, lane = threadIdx.x & 63;
  int m0 = blockIdx.x * 64 + wid * 16;
  int t0 = blockIdx.y * 8;
  int row = m0 + (lane & 15);
  int col = lane & 15, r4 = (lane >> 4) * 4;
  f32x4 acc[8];
#pragma unroll
  for (int j = 0; j < 8; j++) acc[j] = (f32x4){0.f, 0.f, 0.f, 0.f};
#pragma unroll
  for (int ks = 0; ks < 4; ks++) {
    short8 a = *(const short8*)(xbf + (size_t)row * DM_ + ks * 32 + (lane >> 4) * 8);
#pragma unroll
    for (int j = 0; j < 8; j++) {
      short8 b = *(const short8*)(w2p + (((ks * 32 + t0 + j) * 64 + lane) << 3));
      acc[j] = __builtin_amdgcn_mfma_f32_16x16x32_bf16(a, b, acc[j], 0, 0, 0);
    }
  }
#pragma unroll
  for (int j = 0; j < 8; j++) {
    int tg = t0 + j;
    if (tg < 16) {
#pragma unroll
      for (int q = 0; q < 4; q++)
        xi_bf[(size_t)(m0 + r4 + q) * DI_ + tg * 16 + col] = f2bf(acc[j][q]);
    } else {
#pragma unroll
      for (int q = 0; q < 4; q++)
        zb[(size_t)(m0 + r4 + q) * DI_ + (tg - 16) * 16 + col] = f2bf(acc[j][q]);
    }
  }
}

// ---------------- depthwise 3x3 conv + bias + SiLU (bf16 in) -> xs bf16 ----------------
__global__ __launch_bounds__(256) void k_conv(const unsigned short* __restrict__ xi_bf,
                                              const float* __restrict__ cw,
                                              const float* __restrict__ cb,
                                              unsigned short* __restrict__ xs_bf) {
  int wt = blockIdx.x;        // 0..5
  int h  = blockIdx.y;        // 0..95
  int b  = blockIdx.z;        // 0..1
  int d  = threadIdx.x;       // channel
  int w0 = wt * 16;
  float wgt[9];
#pragma unroll
  for (int k = 0; k < 9; k++) wgt[k] = cw[d * 9 + k];
  float bias = cb[d];

  float v[3][18];
#pragma unroll
  for (int r = 0; r < 3; r++) {
    int hh = h - 1 + r;
    bool rok = (hh >= 0) & (hh < H_);
    const unsigned short* rowp = xi_bf + ((size_t)(b * H_ + hh) * W_) * DI_ + d;
#pragma unroll
    for (int j = 0; j < 18; j++) {
      int ww = w0 - 1 + j;
      bool ok = rok & (ww >= 0) & (ww < W_);
      v[r][j] = ok ? bf2f(rowp[(size_t)ww * DI_]) : 0.f;   // block-uniform predicate
    }
  }
#pragma unroll
  for (int j = 0; j < 16; j++) {
    float acc = bias;
#pragma unroll
    for (int r = 0; r < 3; r++)
#pragma unroll
      for (int q = 0; q < 3; q++)
        acc = fmaf(v[r][j + q], wgt[r * 3 + q], acc);
    float sg = 1.0f / (1.0f + __expf(-acc));
    float o = acc * sg;
    size_t bl = (size_t)(b * H_ + h) * W_ + w0 + j;
    xs_bf[bl * DI_ + d] = f2bf(o);
  }
}

// ---------------- x-side MFMA: (BL,256)x(256,288), col-split x3 ----------------
__global__ __launch_bounds__(256) void k_xmfma(const unsigned short* __restrict__ xs_bf,
                                               const unsigned short* __restrict__ wallp,
                                               const float* __restrict__ dtb,
                                               float* __restrict__ delta,
                                               float* __restrict__ Bsb,
                                               float* __restrict__ Csb) {
  int wid = threadIdx.x >> 6, lane = threadIdx.x & 63;
  int m0 = blockIdx.x * 64 + wid * 16;
  int t0 = blockIdx.y * 6;
  int row = m0 + (lane & 15);
  int col = lane & 15, r4 = (lane >> 4) * 4;
  f32x4 acc[6];
#pragma unroll
  for (int j = 0; j < 6; j++) acc[j] = (f32x4){0.f, 0.f, 0.f, 0.f};
#pragma unroll
  for (int ks = 0; ks < 8; ks++) {
    short8 a = *(const short8*)(xs_bf + (size_t)row * DI_ + ks * 32 + (lane >> 4) * 8);
#pragma unroll
    for (int j = 0; j < 6; j++) {
      short8 b = *(const short8*)(wallp + (((ks * 18 + t0 + j) * 64 + lane) << 3));
      acc[j] = __builtin_amdgcn_mfma_f32_16x16x32_bf16(a, b, acc[j], 0, 0, 0);
    }
  }
#pragma unroll
  for (int j = 0; j < 6; j++) {
    int t = t0 + j;
    if (t < 16) {
      float bias = dtb[t * 16 + col];
#pragma unroll
      for (int q = 0; q < 4; q++) {
        float v = acc[j][q] + bias;
        float sp = (v > 20.f) ? v : log1pf(__expf(v));
        delta[(size_t)(m0 + r4 + q) * DI_ + t * 16 + col] = sp;
      }
    } else if (t == 16) {
#pragma unroll
      for (int q = 0; q < 4; q++)
        Bsb[(size_t)(m0 + r4 + q) * DS_ + col] = acc[j][q];
    } else {
#pragma unroll
      for (int q = 0; q < 4; q++)
        Csb[(size_t)(m0 + r4 + q) * DS_ + col] = acc[j][q];
    }
  }
}

// ---------------- Scan pass 1: LDS-staged chunk scan, power-chain dA ----------------
__global__ __launch_bounds__(256, 3) void k_scan1(const float* __restrict__ delta,
                                                  const unsigned short* __restrict__ xs_bf,
                                                  const float* __restrict__ Bsb,
                                                  const float* __restrict__ A_logs,
                                                  float* __restrict__ S_buf,
                                                  float* __restrict__ sumD_buf) {
  int c = blockIdx.x, b = blockIdx.y;
  int d = threadIdx.x;
  __shared__ float sD[CL_][DI_];            // 24 KB
  __shared__ unsigned short sX[CL_][DI_];   // 12 KB
  __shared__ float sB[CL_][DS_];            // 1.5 KB
  size_t base = (size_t)b * L_ + (size_t)c * CL_;
  for (int i = d; i < CL_ * DS_; i += 256)
    sB[i >> 4][i & 15] = Bsb[base * DS_ + i];
  for (int i = d; i < CL_ * DI_ / 4; i += 256)
    ((float4*)sD)[i] = ((const float4*)(delta + base * DI_))[i];
  for (int i = d; i < CL_ * DI_ / 8; i += 256)
    ((short8*)sX)[i] = ((const short8*)(xs_bf + base * DI_))[i];

  float a2_0 = -__expf(A_logs[d * DS_]) * 1.44269504f;
  bool fast = true;
#pragma unroll
  for (int n = 1; n < DS_; n++) {
    float a2n = -__expf(A_logs[d * DS_ + n]) * 1.44269504f;
    fast &= fabsf(a2n - (float)(n + 1) * a2_0) <= 1e-4f * fabsf(a2n);
  }
  __syncthreads();
  float h[DS_];
#pragma unroll
  for (int n = 0; n < DS_; n++) h[n] = 0.f;
  float sum = 0.f;
  if (fast) {
#pragma unroll
    for (int s = 0; s < CL_; s++) {
      float4 b0 = *(const float4*)&sB[s][0];
      float4 b1 = *(const float4*)&sB[s][4];
      float4 b2 = *(const float4*)&sB[s][8];
      float4 b3 = *(const float4*)&sB[s][12];
      float Bv[DS_] = {b0.x,b0.y,b0.z,b0.w, b1.x,b1.y,b1.z,b1.w,
                       b2.x,b2.y,b2.z,b2.w, b3.x,b3.y,b3.z,b3.w};
      float dv = sD[s][d];
      float dvx = dv * bf2f(sX[s][d]);
      sum += dv;
      float pw[DS_];
      float p = exp2f(dv * a2_0);
      POW_TREE(p, pw);
#pragma unroll
      for (int n = 0; n < DS_; n++)
        h[n] = fmaf(pw[n], h[n], dvx * Bv[n]);
    }
  } else {
    float a2[DS_];
#pragma unroll
    for (int n = 0; n < DS_; n++)
      a2[n] = -__expf(A_logs[d * DS_ + n]) * 1.44269504f;
    for (int s = 0; s < CL_; s++) {
      float dv = sD[s][d];
      float dvx = dv * bf2f(sX[s][d]);
      sum += dv;
      for (int n = 0; n < DS_; n++)
        h[n] = fmaf(exp2f(dv * a2[n]), h[n], dvx * sB[s][n]);
    }
  }
  size_t o = ((size_t)(b * C_ + c) * DI_ + d) * DS_;
#pragma unroll
  for (int q = 0; q < 4; q++)
    *(float4*)(S_buf + o + 4 * q) = (float4){h[4*q], h[4*q+1], h[4*q+2], h[4*q+3]};
  sumD_buf[(size_t)(b * C_ + c) * DI_ + d] = sum;
}

// ---------------- Scan pass 2a: group-local chunk prefix (prefetched) ----------------
__global__ __launch_bounds__(256) void k_scan2a(const float* __restrict__ S_buf,
                                                float* __restrict__ sumD_csd,
                                                const float* __restrict__ A_logs,
                                                float* __restrict__ hin_loc,
                                                float* __restrict__ HgS,
                                                float* __restrict__ gsd) {
  int t = blockIdx.x * 256 + threadIdx.x;   // 0 .. B*G*DI*DS-1
  int b = t >> 16;
  int g = (t >> 12) & 15;
  int d = (t >> 4) & 255;
  int n = t & 15;
  float a2 = -__expf(A_logs[d * DS_ + n]) * 1.44269504f;
  float h = 0.f, csd = 0.f;
  int c0 = b * C_ + g * GC_;
  const size_t stride = (size_t)DI_ * DS_;
  size_t o  = ((size_t)c0 * DI_ + d) * DS_ + n;
  size_t od = (size_t)c0 * DI_ + d;
  float S  = S_buf[o];
  float sd = sumD_csd[od];
#pragma unroll
  for (int j = 0; j < GC_; j++) {
    float Sn = 0.f, sdn = 0.f;
    if (j + 1 < GC_) {
      Sn  = S_buf[o + stride];
      sdn = sumD_csd[od + DI_];
    }
    hin_loc[o] = h;
    if (n == 0) sumD_csd[od] = csd;
    csd += sd;
    h = fmaf(exp2f(a2 * sd), h, S);
    S = Sn; sd = sdn;
    o += stride; od += DI_;
  }
  size_t og = ((size_t)(b * G_ + g) * DI_ + d) * DS_ + n;
  HgS[og] = h;
  if (n == 0) gsd[(size_t)(b * G_ + g) * DI_ + d] = csd;
}

// ---------------- Scan pass 2b: combine group summaries ----------------
__global__ __launch_bounds__(256) void k_scan2b(float* __restrict__ HgS_Hpre,
                                                const float* __restrict__ gsd,
                                                const float* __restrict__ A_logs) {
  int t = blockIdx.x * 256 + threadIdx.x;   // 0 .. 8191
  int b = t >> 12;
  int d = (t >> 4) & 255;
  int n = t & 15;
  float a2 = -__expf(A_logs[d * DS_ + n]) * 1.44269504f;
  float h = 0.f;
#pragma unroll
  for (int g = 0; g < G_; g++) {
    size_t o = ((size_t)(b * G_ + g) * DI_ + d) * DS_ + n;
    float Hg = HgS_Hpre[o];
    float sd = gsd[(size_t)(b * G_ + g) * DI_ + d];
    HgS_Hpre[o] = h;
    h = fmaf(exp2f(a2 * sd), h, Hg);
  }
}

// ---------------- Scan pass 3 + LN + SiLU(z) gate + fused out_proj MFMA -> out ----------------
// ysm doubles as delta stage (read [s][d] before y write [s][d]); gls doubles as xs stage.
__global__ __launch_bounds__(256, 3) void k_scan3(const float* __restrict__ delta,
                                                   const unsigned short* __restrict__ xs_bf,
                                                   const float* __restrict__ Bsb,
                                                   const float* __restrict__ Csb,
                                                   const float* __restrict__ A_logs,
                                                   const float* __restrict__ Ds,
                                                   const float* __restrict__ hin_loc,
                                                   const float* __restrict__ Hpre,
                                                   const float* __restrict__ csd,
                                                   const unsigned short* __restrict__ zb,
                                                   const float* __restrict__ lng,
                                                   const float* __restrict__ lnb,
                                                   const unsigned short* __restrict__ wop,
                                                   float* __restrict__ out) {
  int c = blockIdx.x, b = blockIdx.y;
  int d = threadIdx.x;
  int grp = c / GC_;
  __shared__ float ysm[CL_][DI_];           // delta stage -> y
  __shared__ unsigned short gls[32][GP_];   // xs stage -> g tile
  __shared__ float sBC[2][CL_][DS_];
  __shared__ float smu[CL_], srs[CL_];
  size_t base = (size_t)b * L_ + (size_t)c * CL_;
  for (int i = d; i < CL_ * DS_; i += 256) {
    sBC[0][i >> 4][i & 15] = Bsb[base * DS_ + i];
    sBC[1][i >> 4][i & 15] = Csb[base * DS_ + i];
  }
  for (int i = d; i < CL_ * DI_ / 4; i += 256)
    ((float4*)ysm)[i] = ((const float4*)(delta + base * DI_))[i];
  for (int i = d; i < CL_ * 32; i += 256) {
    int row = i >> 5, c8 = i & 31;
    *(short8*)&gls[row][c8 * 8] = ((const short8*)(xs_bf + base * DI_))[i];
  }
  float a2_0 = -__expf(A_logs[d * DS_]) * 1.44269504f;
  bool fast = true;
#pragma unroll
  for (int n = 1; n < DS_; n++) {
    float a2n = -__expf(A_logs[d * DS_ + n]) * 1.44269504f;
    fast &= fabsf(a2n - (float)(n + 1) * a2_0) <= 1e-4f * fabsf(a2n);
  }
  float Dv = Ds[d];
  // seed inputs
  size_t ho = ((size_t)(b * C_ + c) * DI_ + d) * DS_;
  size_t go = ((size_t)(b * G_ + grp) * DI_ + d) * DS_;
  float cs = csd[(size_t)(b * C_ + c) * DI_ + d];
  float h[DS_];
  if (fast) {
    float pw[DS_];
    float p = exp2f(cs * a2_0);
    POW_TREE(p, pw);
#pragma unroll
    for (int q = 0; q < 4; q++) {
      float4 tl = *(const float4*)(hin_loc + ho + 4 * q);
      float4 tp = *(const float4*)(Hpre + go + 4 * q);
      h[4*q+0] = fmaf(pw[4*q+0], tp.x, tl.x);
      h[4*q+1] = fmaf(pw[4*q+1], tp.y, tl.y);
      h[4*q+2] = fmaf(pw[4*q+2], tp.z, tl.z);
      h[4*q+3] = fmaf(pw[4*q+3], tp.w, tl.w);
    }
  } else {
#pragma unroll
    for (int n = 0; n < DS_; n++) {
      float a2n = -__expf(A_logs[d * DS_ + n]) * 1.44269504f;
      h[n] = fmaf(exp2f(cs * a2n), Hpre[go + n], hin_loc[ho + n]);
    }
  }
  __syncthreads();
  if (fast) {
#pragma unroll
    for (int s = 0; s < CL_; s++) {
      float4 b0 = *(const float4*)&sBC[0][s][0];
      float4 b1 = *(const float4*)&sBC[0][s][4];
      float4 b2 = *(const float4*)&sBC[0][s][8];
      float4 b3 = *(const float4*)&sBC[0][s][12];
      float4 c0 = *(const float4*)&sBC[1][s][0];
      float4 c1 = *(const float4*)&sBC[1][s][4];
      float4 c2 = *(const float4*)&sBC[1][s][8];
      float4 c3 = *(const float4*)&sBC[1][s][12];
      float Bv[DS_] = {b0.x,b0.y,b0.z,b0.w, b1.x,b1.y,b1.z,b1.w,
                       b2.x,b2.y,b2.z,b2.w, b3.x,b3.y,b3.z,b3.w};
      float Cv[DS_] = {c0.x,c0.y,c0.z,c0.w, c1.x,c1.y,c1.z,c1.w,
                       c2.x,c2.y,c2.z,c2.w, c3.x,c3.y,c3.z,c3.w};
      float dv = ysm[s][d];
      float xv = bf2f(gls[s][d]);
      float dvx = dv * xv;
      float pw[DS_];
      float p = exp2f(dv * a2_0);
      POW_TREE(p, pw);
      float y0 = Dv * xv, y1 = 0.f, y2 = 0.f, y3 = 0.f;
#pragma unroll
      for (int k = 0; k < 4; k++) {
        int n0 = k, n1_ = 4 + k, n2 = 8 + k, n3 = 12 + k;
        h[n0] = fmaf(pw[n0], h[n0], dvx * Bv[n0]);
        y0 = fmaf(h[n0], Cv[n0], y0);
        h[n1_] = fmaf(pw[n1_], h[n1_], dvx * Bv[n1_]);
        y1 = fmaf(h[n1_], Cv[n1_], y1);
        h[n2] = fmaf(pw[n2], h[n2], dvx * Bv[n2]);
        y2 = fmaf(h[n2], Cv[n2], y2);
        h[n3] = fmaf(pw[n3], h[n3], dvx * Bv[n3]);
        y3 = fmaf(h[n3], Cv[n3], y3);
      }
      ysm[s][d] = (y0 + y1) + (y2 + y3);
    }
  } else {
    float a2[DS_];
#pragma unroll
    for (int n = 0; n < DS_; n++)
      a2[n] = -__expf(A_logs[d * DS_ + n]) * 1.44269504f;
    for (int s = 0; s < CL_; s++) {
      float dv = ysm[s][d];
      float xv = bf2f(gls[s][d]);
      float dvx = dv * xv;
      float yy = Dv * xv;
      for (int n = 0; n < DS_; n++) {
        h[n] = fmaf(exp2f(dv * a2[n]), h[n], dvx * sBC[0][s][n]);
        yy = fmaf(h[n], sBC[1][s][n], yy);
      }
      ysm[s][d] = yy;
    }
  }
  __syncthreads();
  {
    int wid = d >> 6, lane = d & 63;
#pragma unroll
    for (int s6 = 0; s6 < CL_ / 4; s6++) {
      int s = wid * (CL_ / 4) + s6;
      float p0 = ysm[s][lane], p1 = ysm[s][lane + 64];
      float p2 = ysm[s][lane + 128], p3 = ysm[s][lane + 192];
      float s1 = (p0 + p1) + (p2 + p3);
      float s2 = (p0*p0 + p1*p1) + (p2*p2 + p3*p3);
#pragma unroll
      for (int off = 32; off >= 1; off >>= 1) {
        s1 += __shfl_xor(s1, off);
        s2 += __shfl_xor(s2, off);
      }
      if (lane == 0) {
        float mu = s1 / DI_;
        smu[s] = mu;
        srs[s] = rsqrtf(s2 / DI_ - mu * mu + 1e-5f);
      }
    }
  }
  __syncthreads();
  float lg = lng[d], lb = lnb[d];
#pragma unroll
  for (int s = 0; s < CL_; s++) {
    float v = (ysm[s][d] - smu[s]) * srs[s] * lg + lb;
    float zz = bf2f(zb[(base + s) * DI_ + d]);
    float sg = zz / (1.f + __expf(-zz));
    gls[s][d] = f2bf(v * sg);
  }
  __syncthreads();
  // ---- fused out_proj: (24x256) @ (256x128)^T via MFMA; 4 waves x (2 M-tiles x 2 N-tiles)
  {
    int wid = d >> 6, lane = d & 63;
    int colp = lane & 15, r4p = (lane >> 4) * 4;
    int k0 = (lane >> 4) * 8;
    f32x4 oacc[2][2];
#pragma unroll
    for (int mt = 0; mt < 2; mt++)
#pragma unroll
      for (int j = 0; j < 2; j++) oacc[mt][j] = (f32x4){0.f, 0.f, 0.f, 0.f};
#pragma unroll
    for (int ks = 0; ks < 8; ks++) {
      short8 a0 = *(const short8*)&gls[lane & 15][ks * 32 + k0];
      short8 a1 = *(const short8*)&gls[16 + (lane & 15)][ks * 32 + k0];
#pragma unroll
      for (int j = 0; j < 2; j++) {
        int nt = wid * 2 + j;
        short8 bfr = *(const short8*)(wop + (((ks * 8 + nt) * 64 + lane) << 3));
        oacc[0][j] = __builtin_amdgcn_mfma_f32_16x16x32_bf16(a0, bfr, oacc[0][j], 0, 0, 0);
        oacc[1][j] = __builtin_amdgcn_mfma_f32_16x16x32_bf16(a1, bfr, oacc[1][j], 0, 0, 0);
      }
    }
#pragma unroll
    for (int mt = 0; mt < 2; mt++)
#pragma unroll
      for (int j = 0; j < 2; j++) {
        int nt = wid * 2 + j;
#pragma unroll
        for (int q = 0; q < 4; q++) {
          int rl = mt * 16 + r4p + q;
          if (rl < CL_)
            out[(base + rl) * DM_ + nt * 16 + colp] = oacc[mt][j][q];
        }
      }
  }
}

extern "C" void kernel_launch(void* const* d_in, const int* in_sizes, int n_in,
                              void* d_out, int out_size, void* d_ws, size_t ws_size,
                              hipStream_t stream) {
  const float* x         = (const float*)d_in[0];
  const float* in_proj_w = (const float*)d_in[1];
  const float* conv_w    = (const float*)d_in[2];
  const float* conv_b    = (const float*)d_in[3];
  const float* x_proj_w  = (const float*)d_in[4];
  const float* dt_w      = (const float*)d_in[5];
  const float* dt_b      = (const float*)d_in[6];
  const float* A_logs    = (const float*)d_in[7];
  const float* Ds        = (const float*)d_in[8];
  const float* ln_g      = (const float*)d_in[9];
  const float* ln_b      = (const float*)d_in[10];
  const float* out_proj_w= (const float*)d_in[11];
  float* out = (float*)d_out;

  float* ws = (float*)d_ws;
  size_t n1 = (size_t)BL_ * DI_;
  // slot 0: xi bf16 -> S_buf fp32
  unsigned short* xi_bf = (unsigned short*)ws;
  float* S_buf  = ws;
  // slot 1: z bf16 + xs bf16
  unsigned short* z_bf  = (unsigned short*)(ws + n1);
  unsigned short* xs_bf = z_bf + n1;
  // slot 3: delta fp32
  float* delta  = ws + 3 * n1;
  float* Bsb    = ws + 4 * n1;
  float* Csb    = Bsb + (size_t)BL_ * DS_;
  float* hin_loc= Csb + (size_t)BL_ * DS_;                       // 12.6 MB
  float* sumD   = hin_loc + (size_t)B_ * C_ * DI_ * DS_;
  float* HgS    = sumD + (size_t)B_ * C_ * DI_;
  float* gsd    = HgS + (size_t)B_ * G_ * DI_ * DS_;
  unsigned short* wallp = (unsigned short*)(gsd + (size_t)B_ * G_ * DI_);
  unsigned short* w2p   = wallp + 288 * DI_;
  unsigned short* wop   = w2p + 512 * DM_;
  unsigned short* x_bf  = (unsigned short*)hin_loc;  // scratch; dead before scan2a writes

  k_wprep<<<672 + (BL_ * DM_) / 2048, 256, 0, stream>>>(x_proj_w, dt_w, in_proj_w, out_proj_w, x,
                                                        wallp, w2p, wop, x_bf);
  k_in_mfma<<<dim3(BL_ / 64, 4), 256, 0, stream>>>(x_bf, w2p, xi_bf, z_bf);
  k_conv<<<dim3(W_ / 16, H_, B_), 256, 0, stream>>>(xi_bf, conv_w, conv_b, xs_bf);
  k_xmfma<<<dim3(BL_ / 64, 3), 256, 0, stream>>>(xs_bf, wallp, dt_b, delta, Bsb, Csb);
  k_scan1<<<dim3(C_, B_), 256, 0, stream>>>(delta, xs_bf, Bsb, A_logs, S_buf, sumD);
  k_scan2a<<<(B_ * G_ * DI_ * DS_) / 256, 256, 0, stream>>>(S_buf, sumD, A_logs, hin_loc, HgS, gsd);
  k_scan2b<<<(B_ * DI_ * DS_) / 256, 256, 0, stream>>>(HgS, gsd, A_logs);
  k_scan3<<<dim3(C_, B_), 256, 0, stream>>>(delta, xs_bf, Bsb, Csb, A_logs, Ds, hin_loc, HgS, sumD,
                                            z_bf, ln_g, ln_b, wop, out);
}

// Round 13
// 115.535 us; speedup vs baseline: 1.2547x; 1.0673x over previous
//
#include <hip/hip_runtime.h>
#include <math.h>

#define B_ 2
#define H_ 96
#define W_ 96
#define L_ (H_*W_)        // 9216
#define BL_ (B_*L_)       // 18432
#define DM_ 128
#define DI_ 256
#define DS_ 16
#define DR_ 8
#define C_ 384            // chunks per sequence
#define CL_ (L_/C_)       // 24 steps per chunk
#define G_ 16             // chunk groups per sequence
#define GC_ (C_/G_)       // 24 chunks per group
#define GP_ 264           // padded gls row stride (ushorts)

typedef __attribute__((ext_vector_type(8))) short short8;   // 8 bf16 in 4 VGPRs
typedef __attribute__((ext_vector_type(4))) float f32x4;    // MFMA accumulator

static __device__ __forceinline__ unsigned short f2bf(float f) {
  unsigned int u = __float_as_uint(f);
  unsigned int r = (u + 0x7fffu + ((u >> 16) & 1u)) >> 16;  // RNE
  return (unsigned short)r;
}
static __device__ __forceinline__ float bf2f(unsigned short u) {
  return __uint_as_float(((unsigned int)u) << 16);
}

// p^(k+1) for k=0..15 via binary tree (depth 4, 15 muls)
#define POW_TREE(p, pw) \
  pw[0]=(p); pw[1]=pw[0]*pw[0]; pw[2]=pw[1]*pw[0]; pw[3]=pw[1]*pw[1]; \
  pw[4]=pw[3]*pw[0]; pw[5]=pw[3]*pw[1]; pw[6]=pw[3]*pw[2]; pw[7]=pw[3]*pw[3]; \
  pw[8]=pw[7]*pw[0]; pw[9]=pw[7]*pw[1]; pw[10]=pw[7]*pw[2]; pw[11]=pw[7]*pw[3]; \
  pw[12]=pw[7]*pw[4]; pw[13]=pw[7]*pw[5]; pw[14]=pw[7]*pw[6]; pw[15]=pw[7]*pw[7];

// ---------------- Weight prep (packed bf16 fragment panels) + x->bf16 ----------------
__global__ __launch_bounds__(256) void k_wprep(const float* __restrict__ xpw,
                                               const float* __restrict__ dtw,
                                               const float* __restrict__ ipw,
                                               const float* __restrict__ opw,
                                               const float* __restrict__ x,
                                               unsigned short* __restrict__ wallp,
                                               unsigned short* __restrict__ w2p,
                                               unsigned short* __restrict__ wop,
                                               unsigned short* __restrict__ xbf) {
  int bid = blockIdx.x, tid = threadIdx.x;
  if (bid < 288) {                       // Wall: 288 x 256 (K=256, 8 ks, 18 tiles)
    int n = bid, k = tid;
    float v;
    if (n < 256) {
      float s = 0.f;
#pragma unroll
      for (int r = 0; r < DR_; r++) s += xpw[r * DI_ + k] * dtw[n * DR_ + r];
      v = s;
    } else {
      v = xpw[(n - 248) * DI_ + k];      // B rows (8..23) and C rows (24..39)
    }
    int t = n >> 4, col = n & 15, ks = k >> 5, kk = k & 31;
    int lane = (kk >> 3) * 16 + col, i = kk & 7;
    wallp[(((ks * 18 + t) * 64 + lane) << 3) + i] = f2bf(v);
  } else if (bid < 544) {                // in_proj: 512 x 128 (K=128, 4 ks, 32 tiles)
    int n = (bid - 288) * 2 + (tid >> 7), k = tid & 127;
    int t = n >> 4, col = n & 15, ks = k >> 5, kk = k & 31;
    int lane = (kk >> 3) * 16 + col, i = kk & 7;
    w2p[(((ks * 32 + t) * 64 + lane) << 3) + i] = f2bf(ipw[n * DM_ + k]);
  } else if (bid < 672) {                // out_proj: 128 x 256 (K=256, 8 ks, 8 tiles)
    int n = bid - 544, k = tid;
    int t = n >> 4, col = n & 15, ks = k >> 5, kk = k & 31;
    int lane = (kk >> 3) * 16 + col, i = kk & 7;
    wop[(((ks * 8 + t) * 64 + lane) << 3) + i] = f2bf(opw[n * DI_ + k]);
  } else {                               // x -> bf16
    int i = ((bid - 672) * 256 + tid) * 8;
    float4 f0 = *(const float4*)(x + i);
    float4 f1 = *(const float4*)(x + i + 4);
    short8 o;
    o[0]=(short)f2bf(f0.x); o[1]=(short)f2bf(f0.y); o[2]=(short)f2bf(f0.z); o[3]=(short)f2bf(f0.w);
    o[4]=(short)f2bf(f1.x); o[5]=(short)f2bf(f1.y); o[6]=(short)f2bf(f1.z); o[7]=(short)f2bf(f1.w);
    *(short8*)(xbf + i) = o;
  }
}

// ---------------- in_proj MFMA: (BL,128)x(128,512) -> xi bf16 | z bf16, col-split x2 ----------------
__global__ __launch_bounds__(256) void k_in_mfma(const unsigned short* __restrict__ xbf,
                                                 const unsigned short* __restrict__ w2p,
                                                 unsigned short* __restrict__ xi_bf,
                                                 unsigned short* __restrict__ zb) {
  int wid = threadIdx.x >> 6, lane = threadIdx.x & 63;
  int m0 = blockIdx.x * 64 + wid * 16;
  int t0 = blockIdx.y * 16;
  int row = m0 + (lane & 15);
  int col = lane & 15, r4 = (lane >> 4) * 4;
  f32x4 acc[16];
#pragma unroll
  for (int j = 0; j < 16; j++) acc[j] = (f32x4){0.f, 0.f, 0.f, 0.f};
#pragma unroll
  for (int ks = 0; ks < 4; ks++) {
    short8 a = *(const short8*)(xbf + (size_t)row * DM_ + ks * 32 + (lane >> 4) * 8);
#pragma unroll
    for (int j = 0; j < 16; j++) {
      short8 b = *(const short8*)(w2p + (((ks * 32 + t0 + j) * 64 + lane) << 3));
      acc[j] = __builtin_amdgcn_mfma_f32_16x16x32_bf16(a, b, acc[j], 0, 0, 0);
    }
  }
#pragma unroll
  for (int j = 0; j < 16; j++) {
    int tg = t0 + j;
    if (tg < 16) {
#pragma unroll
      for (int q = 0; q < 4; q++)
        xi_bf[(size_t)(m0 + r4 + q) * DI_ + tg * 16 + col] = f2bf(acc[j][q]);
    } else {
#pragma unroll
      for (int q = 0; q < 4; q++)
        zb[(size_t)(m0 + r4 + q) * DI_ + (tg - 16) * 16 + col] = f2bf(acc[j][q]);
    }
  }
}

// ---------------- depthwise 3x3 conv + bias + SiLU, channel-paired ushort2 ----------------
__global__ __launch_bounds__(256, 2) void k_conv(const unsigned short* __restrict__ xi_bf,
                                                 const float* __restrict__ cw,
                                                 const float* __restrict__ cb,
                                                 unsigned short* __restrict__ xs_bf) {
  int wt = blockIdx.x;        // 0..2 (32-wide tiles)
  int h  = blockIdx.y;        // 0..95
  int b  = blockIdx.z;        // 0..1
  int t  = threadIdx.x;
  int wp = t >> 7;            // which 16-wide half
  int cp = t & 127;           // channel pair
  int d0 = cp * 2;
  int w0 = wt * 32 + wp * 16;
  float wgtA[9], wgtB[9];
#pragma unroll
  for (int k = 0; k < 9; k++) { wgtA[k] = cw[d0 * 9 + k]; wgtB[k] = cw[(d0 + 1) * 9 + k]; }
  float biasA = cb[d0], biasB = cb[d0 + 1];

  float vA[3][18], vB[3][18];
#pragma unroll
  for (int r = 0; r < 3; r++) {
    int hh = h - 1 + r;
    bool rok = (hh >= 0) & (hh < H_);
    const unsigned int* rowp = (const unsigned int*)(xi_bf + ((size_t)(b * H_ + hh) * W_) * DI_) + cp;
#pragma unroll
    for (int j = 0; j < 18; j++) {
      int ww = w0 - 1 + j;
      bool ok = rok & (ww >= 0) & (ww < W_);
      unsigned int u = ok ? rowp[(size_t)ww * (DI_ / 2)] : 0u;
      vA[r][j] = bf2f((unsigned short)(u & 0xffffu));
      vB[r][j] = bf2f((unsigned short)(u >> 16));
    }
  }
#pragma unroll
  for (int j = 0; j < 16; j++) {
    float accA = biasA, accB = biasB;
#pragma unroll
    for (int r = 0; r < 3; r++)
#pragma unroll
      for (int q = 0; q < 3; q++) {
        accA = fmaf(vA[r][j + q], wgtA[r * 3 + q], accA);
        accB = fmaf(vB[r][j + q], wgtB[r * 3 + q], accB);
      }
    float oA = accA / (1.f + __expf(-accA));
    float oB = accB / (1.f + __expf(-accB));
    size_t bl = (size_t)(b * H_ + h) * W_ + w0 + j;
    unsigned int o = (unsigned int)f2bf(oA) | ((unsigned int)f2bf(oB) << 16);
    *(unsigned int*)(xs_bf + bl * DI_ + d0) = o;
  }
}

// ---------------- x-side MFMA: (BL,256)x(256,288) -> delta bf16 | Bs | Cs, col-split x3 ----------------
__global__ __launch_bounds__(256) void k_xmfma(const unsigned short* __restrict__ xs_bf,
                                               const unsigned short* __restrict__ wallp,
                                               const float* __restrict__ dtb,
                                               unsigned short* __restrict__ delta_bf,
                                               float* __restrict__ Bsb,
                                               float* __restrict__ Csb) {
  int wid = threadIdx.x >> 6, lane = threadIdx.x & 63;
  int m0 = blockIdx.x * 64 + wid * 16;
  int t0 = blockIdx.y * 6;
  int row = m0 + (lane & 15);
  int col = lane & 15, r4 = (lane >> 4) * 4;
  f32x4 acc[6];
#pragma unroll
  for (int j = 0; j < 6; j++) acc[j] = (f32x4){0.f, 0.f, 0.f, 0.f};
#pragma unroll
  for (int ks = 0; ks < 8; ks++) {
    short8 a = *(const short8*)(xs_bf + (size_t)row * DI_ + ks * 32 + (lane >> 4) * 8);
#pragma unroll
    for (int j = 0; j < 6; j++) {
      short8 b = *(const short8*)(wallp + (((ks * 18 + t0 + j) * 64 + lane) << 3));
      acc[j] = __builtin_amdgcn_mfma_f32_16x16x32_bf16(a, b, acc[j], 0, 0, 0);
    }
  }
#pragma unroll
  for (int j = 0; j < 6; j++) {
    int t = t0 + j;
    if (t < 16) {
      float bias = dtb[t * 16 + col];
#pragma unroll
      for (int q = 0; q < 4; q++) {
        float v = acc[j][q] + bias;
        float sp = (v > 20.f) ? v : log1pf(__expf(v));
        delta_bf[(size_t)(m0 + r4 + q) * DI_ + t * 16 + col] = f2bf(sp);
      }
    } else if (t == 16) {
#pragma unroll
      for (int q = 0; q < 4; q++)
        Bsb[(size_t)(m0 + r4 + q) * DS_ + col] = acc[j][q];
    } else {
#pragma unroll
      for (int q = 0; q < 4; q++)
        Csb[(size_t)(m0 + r4 + q) * DS_ + col] = acc[j][q];
    }
  }
}

// ---------------- Scan pass 1: LDS-staged chunk scan, power-chain dA ----------------
__global__ __launch_bounds__(256, 3) void k_scan1(const unsigned short* __restrict__ delta_bf,
                                                  const unsigned short* __restrict__ xs_bf,
                                                  const float* __restrict__ Bsb,
                                                  const float* __restrict__ A_logs,
                                                  float* __restrict__ S_buf,
                                                  float* __restrict__ sumD_buf) {
  int c = blockIdx.x, b = blockIdx.y;
  int d = threadIdx.x;
  __shared__ float sD[CL_][DI_];            // 24 KB (f32, converted at stage)
  __shared__ unsigned short sX[CL_][DI_];   // 12 KB
  __shared__ float sB[CL_][DS_];            // 1.5 KB
  size_t base = (size_t)b * L_ + (size_t)c * CL_;
  for (int i = d; i < CL_ * DS_; i += 256)
    sB[i >> 4][i & 15] = Bsb[base * DS_ + i];
  for (int i = d; i < CL_ * DI_ / 8; i += 256) {
    short8 v = ((const short8*)(delta_bf + base * DI_))[i];
    float* p = &sD[0][0] + i * 8;
    p[0]=bf2f((unsigned short)v[0]); p[1]=bf2f((unsigned short)v[1]);
    p[2]=bf2f((unsigned short)v[2]); p[3]=bf2f((unsigned short)v[3]);
    p[4]=bf2f((unsigned short)v[4]); p[5]=bf2f((unsigned short)v[5]);
    p[6]=bf2f((unsigned short)v[6]); p[7]=bf2f((unsigned short)v[7]);
  }
  for (int i = d; i < CL_ * DI_ / 8; i += 256)
    ((short8*)sX)[i] = ((const short8*)(xs_bf + base * DI_))[i];

  float a2_0 = -__expf(A_logs[d * DS_]) * 1.44269504f;
  bool fast = true;
#pragma unroll
  for (int n = 1; n < DS_; n++) {
    float a2n = -__expf(A_logs[d * DS_ + n]) * 1.44269504f;
    fast &= fabsf(a2n - (float)(n + 1) * a2_0) <= 1e-4f * fabsf(a2n);
  }
  __syncthreads();
  float h[DS_];
#pragma unroll
  for (int n = 0; n < DS_; n++) h[n] = 0.f;
  float sum = 0.f;
  if (fast) {
#pragma unroll
    for (int s = 0; s < CL_; s++) {
      float4 b0 = *(const float4*)&sB[s][0];
      float4 b1 = *(const float4*)&sB[s][4];
      float4 b2 = *(const float4*)&sB[s][8];
      float4 b3 = *(const float4*)&sB[s][12];
      float Bv[DS_] = {b0.x,b0.y,b0.z,b0.w, b1.x,b1.y,b1.z,b1.w,
                       b2.x,b2.y,b2.z,b2.w, b3.x,b3.y,b3.z,b3.w};
      float dv = sD[s][d];
      float dvx = dv * bf2f(sX[s][d]);
      sum += dv;
      float pw[DS_];
      float p = exp2f(dv * a2_0);
      POW_TREE(p, pw);
#pragma unroll
      for (int n = 0; n < DS_; n++)
        h[n] = fmaf(pw[n], h[n], dvx * Bv[n]);
    }
  } else {
    float a2[DS_];
#pragma unroll
    for (int n = 0; n < DS_; n++)
      a2[n] = -__expf(A_logs[d * DS_ + n]) * 1.44269504f;
    for (int s = 0; s < CL_; s++) {
      float dv = sD[s][d];
      float dvx = dv * bf2f(sX[s][d]);
      sum += dv;
      for (int n = 0; n < DS_; n++)
        h[n] = fmaf(exp2f(dv * a2[n]), h[n], dvx * sB[s][n]);
    }
  }
  size_t o = ((size_t)(b * C_ + c) * DI_ + d) * DS_;
#pragma unroll
  for (int q = 0; q < 4; q++)
    *(float4*)(S_buf + o + 4 * q) = (float4){h[4*q], h[4*q+1], h[4*q+2], h[4*q+3]};
  sumD_buf[(size_t)(b * C_ + c) * DI_ + d] = sum;
}

// ---------------- Scan pass 2a: group-local chunk prefix (prefetched) ----------------
__global__ __launch_bounds__(256) void k_scan2a(const float* __restrict__ S_buf,
                                                float* __restrict__ sumD_csd,
                                                const float* __restrict__ A_logs,
                                                float* __restrict__ hin_loc,
                                                float* __restrict__ HgS,
                                                float* __restrict__ gsd) {
  int t = blockIdx.x * 256 + threadIdx.x;   // 0 .. B*G*DI*DS-1
  int b = t >> 16;
  int g = (t >> 12) & 15;
  int d = (t >> 4) & 255;
  int n = t & 15;
  float a2 = -__expf(A_logs[d * DS_ + n]) * 1.44269504f;
  float h = 0.f, csd = 0.f;
  int c0 = b * C_ + g * GC_;
  const size_t stride = (size_t)DI_ * DS_;
  size_t o  = ((size_t)c0 * DI_ + d) * DS_ + n;
  size_t od = (size_t)c0 * DI_ + d;
  float S  = S_buf[o];
  float sd = sumD_csd[od];
#pragma unroll
  for (int j = 0; j < GC_; j++) {
    float Sn = 0.f, sdn = 0.f;
    if (j + 1 < GC_) {
      Sn  = S_buf[o + stride];
      sdn = sumD_csd[od + DI_];
    }
    hin_loc[o] = h;
    if (n == 0) sumD_csd[od] = csd;
    csd += sd;
    h = fmaf(exp2f(a2 * sd), h, S);
    S = Sn; sd = sdn;
    o += stride; od += DI_;
  }
  size_t og = ((size_t)(b * G_ + g) * DI_ + d) * DS_ + n;
  HgS[og] = h;
  if (n == 0) gsd[(size_t)(b * G_ + g) * DI_ + d] = csd;
}

// ---------------- Scan pass 2b: combine group summaries ----------------
__global__ __launch_bounds__(256) void k_scan2b(float* __restrict__ HgS_Hpre,
                                                const float* __restrict__ gsd,
                                                const float* __restrict__ A_logs) {
  int t = blockIdx.x * 256 + threadIdx.x;   // 0 .. 8191
  int b = t >> 12;
  int d = (t >> 4) & 255;
  int n = t & 15;
  float a2 = -__expf(A_logs[d * DS_ + n]) * 1.44269504f;
  float h = 0.f;
#pragma unroll
  for (int g = 0; g < G_; g++) {
    size_t o = ((size_t)(b * G_ + g) * DI_ + d) * DS_ + n;
    float Hg = HgS_Hpre[o];
    float sd = gsd[(size_t)(b * G_ + g) * DI_ + d];
    HgS_Hpre[o] = h;
    h = fmaf(exp2f(a2 * sd), h, Hg);
  }
}

// ---------------- Scan pass 3 + LN + SiLU(z) gate + fused out_proj MFMA -> out ----------------
// ysm doubles as delta stage (bf16 converted to f32); gls doubles as xs stage.
__global__ __launch_bounds__(256, 3) void k_scan3(const unsigned short* __restrict__ delta_bf,
                                                   const unsigned short* __restrict__ xs_bf,
                                                   const float* __restrict__ Bsb,
                                                   const float* __restrict__ Csb,
                                                   const float* __restrict__ A_logs,
                                                   const float* __restrict__ Ds,
                                                   const float* __restrict__ hin_loc,
                                                   const float* __restrict__ Hpre,
                                                   const float* __restrict__ csd,
                                                   const unsigned short* __restrict__ zb,
                                                   const float* __restrict__ lng,
                                                   const float* __restrict__ lnb,
                                                   const unsigned short* __restrict__ wop,
                                                   float* __restrict__ out) {
  int c = blockIdx.x, b = blockIdx.y;
  int d = threadIdx.x;
  int grp = c / GC_;
  __shared__ float ysm[CL_][DI_];           // delta stage -> y
  __shared__ unsigned short gls[32][GP_];   // xs stage -> g tile
  __shared__ float sBC[2][CL_][DS_];
  __shared__ float smu[CL_], srs[CL_];
  size_t base = (size_t)b * L_ + (size_t)c * CL_;
  for (int i = d; i < CL_ * DS_; i += 256) {
    sBC[0][i >> 4][i & 15] = Bsb[base * DS_ + i];
    sBC[1][i >> 4][i & 15] = Csb[base * DS_ + i];
  }
  for (int i = d; i < CL_ * DI_ / 8; i += 256) {
    short8 v = ((const short8*)(delta_bf + base * DI_))[i];
    float* p = &ysm[0][0] + i * 8;
    p[0]=bf2f((unsigned short)v[0]); p[1]=bf2f((unsigned short)v[1]);
    p[2]=bf2f((unsigned short)v[2]); p[3]=bf2f((unsigned short)v[3]);
    p[4]=bf2f((unsigned short)v[4]); p[5]=bf2f((unsigned short)v[5]);
    p[6]=bf2f((unsigned short)v[6]); p[7]=bf2f((unsigned short)v[7]);
  }
  for (int i = d; i < CL_ * 32; i += 256) {
    int row = i >> 5, c8 = i & 31;
    *(short8*)&gls[row][c8 * 8] = ((const short8*)(xs_bf + base * DI_))[i];
  }
  float a2_0 = -__expf(A_logs[d * DS_]) * 1.44269504f;
  bool fast = true;
#pragma unroll
  for (int n = 1; n < DS_; n++) {
    float a2n = -__expf(A_logs[d * DS_ + n]) * 1.44269504f;
    fast &= fabsf(a2n - (float)(n + 1) * a2_0) <= 1e-4f * fabsf(a2n);
  }
  float Dv = Ds[d];
  size_t ho = ((size_t)(b * C_ + c) * DI_ + d) * DS_;
  size_t go = ((size_t)(b * G_ + grp) * DI_ + d) * DS_;
  float cs = csd[(size_t)(b * C_ + c) * DI_ + d];
  float h[DS_];
  if (fast) {
    float pw[DS_];
    float p = exp2f(cs * a2_0);
    POW_TREE(p, pw);
#pragma unroll
    for (int q = 0; q < 4; q++) {
      float4 tl = *(const float4*)(hin_loc + ho + 4 * q);
      float4 tp = *(const float4*)(Hpre + go + 4 * q);
      h[4*q+0] = fmaf(pw[4*q+0], tp.x, tl.x);
      h[4*q+1] = fmaf(pw[4*q+1], tp.y, tl.y);
      h[4*q+2] = fmaf(pw[4*q+2], tp.z, tl.z);
      h[4*q+3] = fmaf(pw[4*q+3], tp.w, tl.w);
    }
  } else {
#pragma unroll
    for (int n = 0; n < DS_; n++) {
      float a2n = -__expf(A_logs[d * DS_ + n]) * 1.44269504f;
      h[n] = fmaf(exp2f(cs * a2n), Hpre[go + n], hin_loc[ho + n]);
    }
  }
  __syncthreads();
  if (fast) {
#pragma unroll
    for (int s = 0; s < CL_; s++) {
      float4 b0 = *(const float4*)&sBC[0][s][0];
      float4 b1 = *(const float4*)&sBC[0][s][4];
      float4 b2 = *(const float4*)&sBC[0][s][8];
      float4 b3 = *(const float4*)&sBC[0][s][12];
      float4 c0 = *(const float4*)&sBC[1][s][0];
      float4 c1 = *(const float4*)&sBC[1][s][4];
      float4 c2 = *(const float4*)&sBC[1][s][8];
      float4 c3 = *(const float4*)&sBC[1][s][12];
      float Bv[DS_] = {b0.x,b0.y,b0.z,b0.w, b1.x,b1.y,b1.z,b1.w,
                       b2.x,b2.y,b2.z,b2.w, b3.x,b3.y,b3.z,b3.w};
      float Cv[DS_] = {c0.x,c0.y,c0.z,c0.w, c1.x,c1.y,c1.z,c1.w,
                       c2.x,c2.y,c2.z,c2.w, c3.x,c3.y,c3.z,c3.w};
      float dv = ysm[s][d];
      float xv = bf2f(gls[s][d]);
      float dvx = dv * xv;
      float pw[DS_];
      float p = exp2f(dv * a2_0);
      POW_TREE(p, pw);
      float y0 = Dv * xv, y1 = 0.f, y2 = 0.f, y3 = 0.f;
#pragma unroll
      for (int k = 0; k < 4; k++) {
        int n0 = k, n1_ = 4 + k, n2 = 8 + k, n3 = 12 + k;
        h[n0] = fmaf(pw[n0], h[n0], dvx * Bv[n0]);
        y0 = fmaf(h[n0], Cv[n0], y0);
        h[n1_] = fmaf(pw[n1_], h[n1_], dvx * Bv[n1_]);
        y1 = fmaf(h[n1_], Cv[n1_], y1);
        h[n2] = fmaf(pw[n2], h[n2], dvx * Bv[n2]);
        y2 = fmaf(h[n2], Cv[n2], y2);
        h[n3] = fmaf(pw[n3], h[n3], dvx * Bv[n3]);
        y3 = fmaf(h[n3], Cv[n3], y3);
      }
      ysm[s][d] = (y0 + y1) + (y2 + y3);
    }
  } else {
    float a2[DS_];
#pragma unroll
    for (int n = 0; n < DS_; n++)
      a2[n] = -__expf(A_logs[d * DS_ + n]) * 1.44269504f;
    for (int s = 0; s < CL_; s++) {
      float dv = ysm[s][d];
      float xv = bf2f(gls[s][d]);
      float dvx = dv * xv;
      float yy = Dv * xv;
      for (int n = 0; n < DS_; n++) {
        h[n] = fmaf(exp2f(dv * a2[n]), h[n], dvx * sBC[0][s][n]);
        yy = fmaf(h[n], sBC[1][s][n], yy);
      }
      ysm[s][d] = yy;
    }
  }
  __syncthreads();
  {
    int wid = d >> 6, lane = d & 63;
#pragma unroll
    for (int s6 = 0; s6 < CL_ / 4; s6++) {
      int s = wid * (CL_ / 4) + s6;
      float p0 = ysm[s][lane], p1 = ysm[s][lane + 64];
      float p2 = ysm[s][lane + 128], p3 = ysm[s][lane + 192];
      float s1 = (p0 + p1) + (p2 + p3);
      float s2 = (p0*p0 + p1*p1) + (p2*p2 + p3*p3);
#pragma unroll
      for (int off = 32; off >= 1; off >>= 1) {
        s1 += __shfl_xor(s1, off);
        s2 += __shfl_xor(s2, off);
      }
      if (lane == 0) {
        float mu = s1 / DI_;
        smu[s] = mu;
        srs[s] = rsqrtf(s2 / DI_ - mu * mu + 1e-5f);
      }
    }
  }
  __syncthreads();
  float lg = lng[d], lb = lnb[d];
#pragma unroll
  for (int s = 0; s < CL_; s++) {
    float v = (ysm[s][d] - smu[s]) * srs[s] * lg + lb;
    float zz = bf2f(zb[(base + s) * DI_ + d]);
    float sg = zz / (1.f + __expf(-zz));
    gls[s][d] = f2bf(v * sg);
  }
  __syncthreads();
  // ---- fused out_proj: (24x256) @ (256x128)^T via MFMA; 4 waves x (2 M-tiles x 2 N-tiles)
  {
    int wid = d >> 6, lane = d & 63;
    int colp = lane & 15, r4p = (lane >> 4) * 4;
    int k0 = (lane >> 4) * 8;
    f32x4 oacc[2][2];
#pragma unroll
    for (int mt = 0; mt < 2; mt++)
#pragma unroll
      for (int j = 0; j < 2; j++) oacc[mt][j] = (f32x4){0.f, 0.f, 0.f, 0.f};
#pragma unroll
    for (int ks = 0; ks < 8; ks++) {
      short8 a0 = *(const short8*)&gls[lane & 15][ks * 32 + k0];
      short8 a1 = *(const short8*)&gls[16 + (lane & 15)][ks * 32 + k0];
#pragma unroll
      for (int j = 0; j < 2; j++) {
        int nt = wid * 2 + j;
        short8 bfr = *(const short8*)(wop + (((ks * 8 + nt) * 64 + lane) << 3));
        oacc[0][j] = __builtin_amdgcn_mfma_f32_16x16x32_bf16(a0, bfr, oacc[0][j], 0, 0, 0);
        oacc[1][j] = __builtin_amdgcn_mfma_f32_16x16x32_bf16(a1, bfr, oacc[1][j], 0, 0, 0);
      }
    }
#pragma unroll
    for (int mt = 0; mt < 2; mt++)
#pragma unroll
      for (int j = 0; j < 2; j++) {
        int nt = wid * 2 + j;
#pragma unroll
        for (int q = 0; q < 4; q++) {
          int rl = mt * 16 + r4p + q;
          if (rl < CL_)
            out[(base + rl) * DM_ + nt * 16 + colp] = oacc[mt][j][q];
        }
      }
  }
}

extern "C" void kernel_launch(void* const* d_in, const int* in_sizes, int n_in,
                              void* d_out, int out_size, void* d_ws, size_t ws_size,
                              hipStream_t stream) {
  const float* x         = (const float*)d_in[0];
  const float* in_proj_w = (const float*)d_in[1];
  const float* conv_w    = (const float*)d_in[2];
  const float* conv_b    = (const float*)d_in[3];
  const float* x_proj_w  = (const float*)d_in[4];
  const float* dt_w      = (const float*)d_in[5];
  const float* dt_b      = (const float*)d_in[6];
  const float* A_logs    = (const float*)d_in[7];
  const float* Ds        = (const float*)d_in[8];
  const float* ln_g      = (const float*)d_in[9];
  const float* ln_b      = (const float*)d_in[10];
  const float* out_proj_w= (const float*)d_in[11];
  float* out = (float*)d_out;

  float* ws = (float*)d_ws;
  size_t n1 = (size_t)BL_ * DI_;
  // slot 0: xi bf16 -> S_buf fp32
  unsigned short* xi_bf = (unsigned short*)ws;
  float* S_buf  = ws;
  // slot 1: z bf16 + xs bf16
  unsigned short* z_bf  = (unsigned short*)(ws + n1);
  unsigned short* xs_bf = z_bf + n1;
  // slot 3: delta bf16 (uses half of old fp32 slot)
  unsigned short* delta_bf = (unsigned short*)(ws + 3 * n1);
  float* Bsb    = ws + 4 * n1;
  float* Csb    = Bsb + (size_t)BL_ * DS_;
  float* hin_loc= Csb + (size_t)BL_ * DS_;                       // 12.6 MB
  float* sumD   = hin_loc + (size_t)B_ * C_ * DI_ * DS_;
  float* HgS    = sumD + (size_t)B_ * C_ * DI_;
  float* gsd    = HgS + (size_t)B_ * G_ * DI_ * DS_;
  unsigned short* wallp = (unsigned short*)(gsd + (size_t)B_ * G_ * DI_);
  unsigned short* w2p   = wallp + 288 * DI_;
  unsigned short* wop   = w2p + 512 * DM_;
  unsigned short* x_bf  = (unsigned short*)hin_loc;  // scratch; dead before scan2a writes

  k_wprep<<<672 + (BL_ * DM_) / 2048, 256, 0, stream>>>(x_proj_w, dt_w, in_proj_w, out_proj_w, x,
                                                        wallp, w2p, wop, x_bf);
  k_in_mfma<<<dim3(BL_ / 64, 2), 256, 0, stream>>>(x_bf, w2p, xi_bf, z_bf);
  k_conv<<<dim3(W_ / 32, H_, B_), 256, 0, stream>>>(xi_bf, conv_w, conv_b, xs_bf);
  k_xmfma<<<dim3(BL_ / 64, 3), 256, 0, stream>>>(xs_bf, wallp, dt_b, delta_bf, Bsb, Csb);
  k_scan1<<<dim3(C_, B_), 256, 0, stream>>>(delta_bf, xs_bf, Bsb, A_logs, S_buf, sumD);
  k_scan2a<<<(B_ * G_ * DI_ * DS_) / 256, 256, 0, stream>>>(S_buf, sumD, A_logs, hin_loc, HgS, gsd);
  k_scan2b<<<(B_ * DI_ * DS_) / 256, 256, 0, stream>>>(HgS, gsd, A_logs);
  k_scan3<<<dim3(C_, B_), 256, 0, stream>>>(delta_bf, xs_bf, Bsb, Csb, A_logs, Ds, hin_loc, HgS, sumD,
                                            z_bf, ln_g, ln_b, wop, out);
}

// Round 15
// 112.030 us; speedup vs baseline: 1.2940x; 1.0313x over previous
//
#include <hip/hip_runtime.h>
#include <math.h>

#define B_ 2
#define H_ 96
#define W_ 96
#define L_ (H_*W_)        // 9216
#define BL_ (B_*L_)       // 18432
#define DM_ 128
#define DI_ 256
#define DS_ 16
#define DR_ 8
#define C_ 384            // chunks per sequence
#define CL_ (L_/C_)       // 24 steps per chunk
#define G_ 16             // chunk groups per sequence
#define GC_ (C_/G_)       // 24 chunks per group
#define GP_ 264           // padded gls row stride (ushorts)

typedef __attribute__((ext_vector_type(8))) short short8;   // 8 bf16 in 4 VGPRs
typedef __attribute__((ext_vector_type(4))) float f32x4;    // MFMA accumulator

static __device__ __forceinline__ unsigned short f2bf(float f) {
  unsigned int u = __float_as_uint(f);
  unsigned int r = (u + 0x7fffu + ((u >> 16) & 1u)) >> 16;  // RNE
  return (unsigned short)r;
}
static __device__ __forceinline__ float bf2f(unsigned short u) {
  return __uint_as_float(((unsigned int)u) << 16);
}

// p^(k+1) for k=0..15 via binary tree (depth 4, 15 muls)
#define POW_TREE(p, pw) \
  pw[0]=(p); pw[1]=pw[0]*pw[0]; pw[2]=pw[1]*pw[0]; pw[3]=pw[1]*pw[1]; \
  pw[4]=pw[3]*pw[0]; pw[5]=pw[3]*pw[1]; pw[6]=pw[3]*pw[2]; pw[7]=pw[3]*pw[3]; \
  pw[8]=pw[7]*pw[0]; pw[9]=pw[7]*pw[1]; pw[10]=pw[7]*pw[2]; pw[11]=pw[7]*pw[3]; \
  pw[12]=pw[7]*pw[4]; pw[13]=pw[7]*pw[5]; pw[14]=pw[7]*pw[6]; pw[15]=pw[7]*pw[7];

// ---------------- Weight prep (packed bf16 fragment panels) + x->bf16 ----------------
__global__ __launch_bounds__(256) void k_wprep(const float* __restrict__ xpw,
                                               const float* __restrict__ dtw,
                                               const float* __restrict__ ipw,
                                               const float* __restrict__ opw,
                                               const float* __restrict__ x,
                                               unsigned short* __restrict__ wallp,
                                               unsigned short* __restrict__ w2p,
                                               unsigned short* __restrict__ wop,
                                               unsigned short* __restrict__ xbf) {
  int bid = blockIdx.x, tid = threadIdx.x;
  if (bid < 288) {                       // Wall: 288 x 256 (K=256, 8 ks, 18 tiles)
    int n = bid, k = tid;
    float v;
    if (n < 256) {
      float s = 0.f;
#pragma unroll
      for (int r = 0; r < DR_; r++) s += xpw[r * DI_ + k] * dtw[n * DR_ + r];
      v = s;
    } else {
      v = xpw[(n - 248) * DI_ + k];      // B rows (8..23) and C rows (24..39)
    }
    int t = n >> 4, col = n & 15, ks = k >> 5, kk = k & 31;
    int lane = (kk >> 3) * 16 + col, i = kk & 7;
    wallp[(((ks * 18 + t) * 64 + lane) << 3) + i] = f2bf(v);
  } else if (bid < 544) {                // in_proj: 512 x 128 (K=128, 4 ks, 32 tiles)
    int n = (bid - 288) * 2 + (tid >> 7), k = tid & 127;
    int t = n >> 4, col = n & 15, ks = k >> 5, kk = k & 31;
    int lane = (kk >> 3) * 16 + col, i = kk & 7;
    w2p[(((ks * 32 + t) * 64 + lane) << 3) + i] = f2bf(ipw[n * DM_ + k]);
  } else if (bid < 672) {                // out_proj: 128 x 256 (K=256, 8 ks, 8 tiles)
    int n = bid - 544, k = tid;
    int t = n >> 4, col = n & 15, ks = k >> 5, kk = k & 31;
    int lane = (kk >> 3) * 16 + col, i = kk & 7;
    wop[(((ks * 8 + t) * 64 + lane) << 3) + i] = f2bf(opw[n * DI_ + k]);
  } else {                               // x -> bf16
    int i = ((bid - 672) * 256 + tid) * 8;
    float4 f0 = *(const float4*)(x + i);
    float4 f1 = *(const float4*)(x + i + 4);
    short8 o;
    o[0]=(short)f2bf(f0.x); o[1]=(short)f2bf(f0.y); o[2]=(short)f2bf(f0.z); o[3]=(short)f2bf(f0.w);
    o[4]=(short)f2bf(f1.x); o[5]=(short)f2bf(f1.y); o[6]=(short)f2bf(f1.z); o[7]=(short)f2bf(f1.w);
    *(short8*)(xbf + i) = o;
  }
}

// ---------------- in_proj MFMA: (BL,128)x(128,512) -> xi bf16 | z bf16, col-split x2 ----------------
__global__ __launch_bounds__(256) void k_in_mfma(const unsigned short* __restrict__ xbf,
                                                 const unsigned short* __restrict__ w2p,
                                                 unsigned short* __restrict__ xi_bf,
                                                 unsigned short* __restrict__ zb) {
  int wid = threadIdx.x >> 6, lane = threadIdx.x & 63;
  int m0 = blockIdx.x * 64 + wid * 16;
  int t0 = blockIdx.y * 16;
  int row = m0 + (lane & 15);
  int col = lane & 15, r4 = (lane >> 4) * 4;
  f32x4 acc[16];
#pragma unroll
  for (int j = 0; j < 16; j++) acc[j] = (f32x4){0.f, 0.f, 0.f, 0.f};
#pragma unroll
  for (int ks = 0; ks < 4; ks++) {
    short8 a = *(const short8*)(xbf + (size_t)row * DM_ + ks * 32 + (lane >> 4) * 8);
#pragma unroll
    for (int j = 0; j < 16; j++) {
      short8 b = *(const short8*)(w2p + (((ks * 32 + t0 + j) * 64 + lane) << 3));
      acc[j] = __builtin_amdgcn_mfma_f32_16x16x32_bf16(a, b, acc[j], 0, 0, 0);
    }
  }
#pragma unroll
  for (int j = 0; j < 16; j++) {
    int tg = t0 + j;
    if (tg < 16) {
#pragma unroll
      for (int q = 0; q < 4; q++)
        xi_bf[(size_t)(m0 + r4 + q) * DI_ + tg * 16 + col] = f2bf(acc[j][q]);
    } else {
#pragma unroll
      for (int q = 0; q < 4; q++)
        zb[(size_t)(m0 + r4 + q) * DI_ + (tg - 16) * 16 + col] = f2bf(acc[j][q]);
    }
  }
}

// ---------------- depthwise 3x3 conv + bias + SiLU, channel-paired ushort2 ----------------
__global__ __launch_bounds__(256, 2) void k_conv(const unsigned short* __restrict__ xi_bf,
                                                 const float* __restrict__ cw,
                                                 const float* __restrict__ cb,
                                                 unsigned short* __restrict__ xs_bf) {
  int wt = blockIdx.x;        // 0..2 (32-wide tiles)
  int h  = blockIdx.y;        // 0..95
  int b  = blockIdx.z;        // 0..1
  int t  = threadIdx.x;
  int wp = t >> 7;            // which 16-wide half
  int cp = t & 127;           // channel pair
  int d0 = cp * 2;
  int w0 = wt * 32 + wp * 16;
  float wgtA[9], wgtB[9];
#pragma unroll
  for (int k = 0; k < 9; k++) { wgtA[k] = cw[d0 * 9 + k]; wgtB[k] = cw[(d0 + 1) * 9 + k]; }
  float biasA = cb[d0], biasB = cb[d0 + 1];

  float vA[3][18], vB[3][18];
#pragma unroll
  for (int r = 0; r < 3; r++) {
    int hh = h - 1 + r;
    bool rok = (hh >= 0) & (hh < H_);
    const unsigned int* rowp = (const unsigned int*)(xi_bf + ((size_t)(b * H_ + hh) * W_) * DI_) + cp;
#pragma unroll
    for (int j = 0; j < 18; j++) {
      int ww = w0 - 1 + j;
      bool ok = rok & (ww >= 0) & (ww < W_);
      unsigned int u = ok ? rowp[(size_t)ww * (DI_ / 2)] : 0u;
      vA[r][j] = bf2f((unsigned short)(u & 0xffffu));
      vB[r][j] = bf2f((unsigned short)(u >> 16));
    }
  }
#pragma unroll
  for (int j = 0; j < 16; j++) {
    float accA = biasA, accB = biasB;
#pragma unroll
    for (int r = 0; r < 3; r++)
#pragma unroll
      for (int q = 0; q < 3; q++) {
        accA = fmaf(vA[r][j + q], wgtA[r * 3 + q], accA);
        accB = fmaf(vB[r][j + q], wgtB[r * 3 + q], accB);
      }
    float oA = accA / (1.f + __expf(-accA));
    float oB = accB / (1.f + __expf(-accB));
    size_t bl = (size_t)(b * H_ + h) * W_ + w0 + j;
    unsigned int o = (unsigned int)f2bf(oA) | ((unsigned int)f2bf(oB) << 16);
    *(unsigned int*)(xs_bf + bl * DI_ + d0) = o;
  }
}

// ---------------- x-side MFMA: (BL,256)x(256,288) -> delta bf16 | Bs | Cs, col-split x3 ----------------
__global__ __launch_bounds__(256) void k_xmfma(const unsigned short* __restrict__ xs_bf,
                                               const unsigned short* __restrict__ wallp,
                                               const float* __restrict__ dtb,
                                               unsigned short* __restrict__ delta_bf,
                                               float* __restrict__ Bsb,
                                               float* __restrict__ Csb) {
  int wid = threadIdx.x >> 6, lane = threadIdx.x & 63;
  int m0 = blockIdx.x * 64 + wid * 16;
  int t0 = blockIdx.y * 6;
  int row = m0 + (lane & 15);
  int col = lane & 15, r4 = (lane >> 4) * 4;
  f32x4 acc[6];
#pragma unroll
  for (int j = 0; j < 6; j++) acc[j] = (f32x4){0.f, 0.f, 0.f, 0.f};
#pragma unroll
  for (int ks = 0; ks < 8; ks++) {
    short8 a = *(const short8*)(xs_bf + (size_t)row * DI_ + ks * 32 + (lane >> 4) * 8);
#pragma unroll
    for (int j = 0; j < 6; j++) {
      short8 b = *(const short8*)(wallp + (((ks * 18 + t0 + j) * 64 + lane) << 3));
      acc[j] = __builtin_amdgcn_mfma_f32_16x16x32_bf16(a, b, acc[j], 0, 0, 0);
    }
  }
#pragma unroll
  for (int j = 0; j < 6; j++) {
    int t = t0 + j;
    if (t < 16) {
      float bias = dtb[t * 16 + col];
#pragma unroll
      for (int q = 0; q < 4; q++) {
        float v = acc[j][q] + bias;
        float sp = (v > 20.f) ? v : log1pf(__expf(v));
        delta_bf[(size_t)(m0 + r4 + q) * DI_ + t * 16 + col] = f2bf(sp);
      }
    } else if (t == 16) {
#pragma unroll
      for (int q = 0; q < 4; q++)
        Bsb[(size_t)(m0 + r4 + q) * DS_ + col] = acc[j][q];
    } else {
#pragma unroll
      for (int q = 0; q < 4; q++)
        Csb[(size_t)(m0 + r4 + q) * DS_ + col] = acc[j][q];
    }
  }
}

// ---------------- Scan pass 1: LDS-staged chunk scan, power-chain dA; S stored bf16 ----------------
__global__ __launch_bounds__(256, 3) void k_scan1(const unsigned short* __restrict__ delta_bf,
                                                  const unsigned short* __restrict__ xs_bf,
                                                  const float* __restrict__ Bsb,
                                                  const float* __restrict__ A_logs,
                                                  unsigned short* __restrict__ S_buf,
                                                  float* __restrict__ sumD_buf) {
  int c = blockIdx.x, b = blockIdx.y;
  int d = threadIdx.x;
  __shared__ float sD[CL_][DI_];            // 24 KB (f32, converted at stage)
  __shared__ unsigned short sX[CL_][DI_];   // 12 KB
  __shared__ float sB[CL_][DS_];            // 1.5 KB
  size_t base = (size_t)b * L_ + (size_t)c * CL_;
  for (int i = d; i < CL_ * DS_; i += 256)
    sB[i >> 4][i & 15] = Bsb[base * DS_ + i];
  for (int i = d; i < CL_ * DI_ / 8; i += 256) {
    short8 v = ((const short8*)(delta_bf + base * DI_))[i];
    float* p = &sD[0][0] + i * 8;
    p[0]=bf2f((unsigned short)v[0]); p[1]=bf2f((unsigned short)v[1]);
    p[2]=bf2f((unsigned short)v[2]); p[3]=bf2f((unsigned short)v[3]);
    p[4]=bf2f((unsigned short)v[4]); p[5]=bf2f((unsigned short)v[5]);
    p[6]=bf2f((unsigned short)v[6]); p[7]=bf2f((unsigned short)v[7]);
  }
  for (int i = d; i < CL_ * DI_ / 8; i += 256)
    ((short8*)sX)[i] = ((const short8*)(xs_bf + base * DI_))[i];

  float a2_0 = -__expf(A_logs[d * DS_]) * 1.44269504f;
  bool fast = true;
#pragma unroll
  for (int n = 1; n < DS_; n++) {
    float a2n = -__expf(A_logs[d * DS_ + n]) * 1.44269504f;
    fast &= fabsf(a2n - (float)(n + 1) * a2_0) <= 1e-4f * fabsf(a2n);
  }
  __syncthreads();
  float h[DS_];
#pragma unroll
  for (int n = 0; n < DS_; n++) h[n] = 0.f;
  float sum = 0.f;
  if (fast) {
#pragma unroll
    for (int s = 0; s < CL_; s++) {
      float4 b0 = *(const float4*)&sB[s][0];
      float4 b1 = *(const float4*)&sB[s][4];
      float4 b2 = *(const float4*)&sB[s][8];
      float4 b3 = *(const float4*)&sB[s][12];
      float Bv[DS_] = {b0.x,b0.y,b0.z,b0.w, b1.x,b1.y,b1.z,b1.w,
                       b2.x,b2.y,b2.z,b2.w, b3.x,b3.y,b3.z,b3.w};
      float dv = sD[s][d];
      float dvx = dv * bf2f(sX[s][d]);
      sum += dv;
      float pw[DS_];
      float p = exp2f(dv * a2_0);
      POW_TREE(p, pw);
#pragma unroll
      for (int n = 0; n < DS_; n++)
        h[n] = fmaf(pw[n], h[n], dvx * Bv[n]);
    }
  } else {
    float a2[DS_];
#pragma unroll
    for (int n = 0; n < DS_; n++)
      a2[n] = -__expf(A_logs[d * DS_ + n]) * 1.44269504f;
    for (int s = 0; s < CL_; s++) {
      float dv = sD[s][d];
      float dvx = dv * bf2f(sX[s][d]);
      sum += dv;
      for (int n = 0; n < DS_; n++)
        h[n] = fmaf(exp2f(dv * a2[n]), h[n], dvx * sB[s][n]);
    }
  }
  size_t o = ((size_t)(b * C_ + c) * DI_ + d) * DS_;
  short8 s0, s1;
#pragma unroll
  for (int q = 0; q < 8; q++) s0[q] = (short)f2bf(h[q]);
#pragma unroll
  for (int q = 0; q < 8; q++) s1[q] = (short)f2bf(h[8 + q]);
  *(short8*)(S_buf + o) = s0;
  *(short8*)(S_buf + o + 8) = s1;
  sumD_buf[(size_t)(b * C_ + c) * DI_ + d] = sum;
}

// ---------------- Scan pass 2a: group-local chunk prefix (bf16 S in, bf16 hin out) ----------------
__global__ __launch_bounds__(256) void k_scan2a(const unsigned short* __restrict__ S_buf,
                                                float* __restrict__ sumD_csd,
                                                const float* __restrict__ A_logs,
                                                unsigned short* __restrict__ hin_loc,
                                                float* __restrict__ HgS,
                                                float* __restrict__ gsd) {
  int t = blockIdx.x * 256 + threadIdx.x;   // 0 .. B*G*DI*DS-1
  int b = t >> 16;
  int g = (t >> 12) & 15;
  int d = (t >> 4) & 255;
  int n = t & 15;
  float a2 = -__expf(A_logs[d * DS_ + n]) * 1.44269504f;
  float h = 0.f, csd = 0.f;
  int c0 = b * C_ + g * GC_;
  const size_t stride = (size_t)DI_ * DS_;
  size_t o  = ((size_t)c0 * DI_ + d) * DS_ + n;
  size_t od = (size_t)c0 * DI_ + d;
  float S  = bf2f(S_buf[o]);
  float sd = sumD_csd[od];
#pragma unroll
  for (int j = 0; j < GC_; j++) {
    float Sn = 0.f, sdn = 0.f;
    if (j + 1 < GC_) {
      Sn  = bf2f(S_buf[o + stride]);
      sdn = sumD_csd[od + DI_];
    }
    hin_loc[o] = f2bf(h);
    if (n == 0) sumD_csd[od] = csd;
    csd += sd;
    h = fmaf(exp2f(a2 * sd), h, S);
    S = Sn; sd = sdn;
    o += stride; od += DI_;
  }
  size_t og = ((size_t)(b * G_ + g) * DI_ + d) * DS_ + n;
  HgS[og] = h;
  if (n == 0) gsd[(size_t)(b * G_ + g) * DI_ + d] = csd;
}

// ---------------- Scan pass 2b: combine group summaries ----------------
__global__ __launch_bounds__(256) void k_scan2b(float* __restrict__ HgS_Hpre,
                                                const float* __restrict__ gsd,
                                                const float* __restrict__ A_logs) {
  int t = blockIdx.x * 256 + threadIdx.x;   // 0 .. 8191
  int b = t >> 12;
  int d = (t >> 4) & 255;
  int n = t & 15;
  float a2 = -__expf(A_logs[d * DS_ + n]) * 1.44269504f;
  float h = 0.f;
#pragma unroll
  for (int g = 0; g < G_; g++) {
    size_t o = ((size_t)(b * G_ + g) * DI_ + d) * DS_ + n;
    float Hg = HgS_Hpre[o];
    float sd = gsd[(size_t)(b * G_ + g) * DI_ + d];
    HgS_Hpre[o] = h;
    h = fmaf(exp2f(a2 * sd), h, Hg);
  }
}

// ---------------- Scan pass 3 + LN + SiLU(z) gate + fused out_proj MFMA -> out ----------------
// ysm doubles as delta stage (bf16 converted to f32); gls doubles as xs stage.
__global__ __launch_bounds__(256, 3) void k_scan3(const unsigned short* __restrict__ delta_bf,
                                                   const unsigned short* __restrict__ xs_bf,
                                                   const float* __restrict__ Bsb,
                                                   const float* __restrict__ Csb,
                                                   const float* __restrict__ A_logs,
                                                   const float* __restrict__ Ds,
                                                   const unsigned short* __restrict__ hin_loc,
                                                   const float* __restrict__ Hpre,
                                                   const float* __restrict__ csd,
                                                   const unsigned short* __restrict__ zb,
                                                   const float* __restrict__ lng,
                                                   const float* __restrict__ lnb,
                                                   const unsigned short* __restrict__ wop,
                                                   float* __restrict__ out) {
  int c = blockIdx.x, b = blockIdx.y;
  int d = threadIdx.x;
  int grp = c / GC_;
  __shared__ float ysm[CL_][DI_];           // delta stage -> y
  __shared__ unsigned short gls[32][GP_];   // xs stage -> g tile
  __shared__ float sBC[2][CL_][DS_];
  __shared__ float smu[CL_], srs[CL_];
  size_t base = (size_t)b * L_ + (size_t)c * CL_;
  for (int i = d; i < CL_ * DS_; i += 256) {
    sBC[0][i >> 4][i & 15] = Bsb[base * DS_ + i];
    sBC[1][i >> 4][i & 15] = Csb[base * DS_ + i];
  }
  for (int i = d; i < CL_ * DI_ / 8; i += 256) {
    short8 v = ((const short8*)(delta_bf + base * DI_))[i];
    float* p = &ysm[0][0] + i * 8;
    p[0]=bf2f((unsigned short)v[0]); p[1]=bf2f((unsigned short)v[1]);
    p[2]=bf2f((unsigned short)v[2]); p[3]=bf2f((unsigned short)v[3]);
    p[4]=bf2f((unsigned short)v[4]); p[5]=bf2f((unsigned short)v[5]);
    p[6]=bf2f((unsigned short)v[6]); p[7]=bf2f((unsigned short)v[7]);
  }
  for (int i = d; i < CL_ * 32; i += 256) {
    int row = i >> 5, c8 = i & 31;
    *(short8*)&gls[row][c8 * 8] = ((const short8*)(xs_bf + base * DI_))[i];
  }
  float a2_0 = -__expf(A_logs[d * DS_]) * 1.44269504f;
  bool fast = true;
#pragma unroll
  for (int n = 1; n < DS_; n++) {
    float a2n = -__expf(A_logs[d * DS_ + n]) * 1.44269504f;
    fast &= fabsf(a2n - (float)(n + 1) * a2_0) <= 1e-4f * fabsf(a2n);
  }
  float Dv = Ds[d];
  size_t ho = ((size_t)(b * C_ + c) * DI_ + d) * DS_;
  size_t go = ((size_t)(b * G_ + grp) * DI_ + d) * DS_;
  float cs = csd[(size_t)(b * C_ + c) * DI_ + d];
  float h[DS_];
  {
    short8 t0 = *(const short8*)(hin_loc + ho);
    short8 t1 = *(const short8*)(hin_loc + ho + 8);
    float tl[DS_];
#pragma unroll
    for (int q = 0; q < 8; q++) tl[q] = bf2f((unsigned short)t0[q]);
#pragma unroll
    for (int q = 0; q < 8; q++) tl[8 + q] = bf2f((unsigned short)t1[q]);
    if (fast) {
      float pw[DS_];
      float p = exp2f(cs * a2_0);
      POW_TREE(p, pw);
#pragma unroll
      for (int q = 0; q < 4; q++) {
        float4 tp = *(const float4*)(Hpre + go + 4 * q);
        h[4*q+0] = fmaf(pw[4*q+0], tp.x, tl[4*q+0]);
        h[4*q+1] = fmaf(pw[4*q+1], tp.y, tl[4*q+1]);
        h[4*q+2] = fmaf(pw[4*q+2], tp.z, tl[4*q+2]);
        h[4*q+3] = fmaf(pw[4*q+3], tp.w, tl[4*q+3]);
      }
    } else {
#pragma unroll
      for (int n = 0; n < DS_; n++) {
        float a2n = -__expf(A_logs[d * DS_ + n]) * 1.44269504f;
        h[n] = fmaf(exp2f(cs * a2n), Hpre[go + n], tl[n]);
      }
    }
  }
  __syncthreads();
  if (fast) {
#pragma unroll
    for (int s = 0; s < CL_; s++) {
      float4 b0 = *(const float4*)&sBC[0][s][0];
      float4 b1 = *(const float4*)&sBC[0][s][4];
      float4 b2 = *(const float4*)&sBC[0][s][8];
      float4 b3 = *(const float4*)&sBC[0][s][12];
      float4 c0 = *(const float4*)&sBC[1][s][0];
      float4 c1 = *(const float4*)&sBC[1][s][4];
      float4 c2 = *(const float4*)&sBC[1][s][8];
      float4 c3 = *(const float4*)&sBC[1][s][12];
      float Bv[DS_] = {b0.x,b0.y,b0.z,b0.w, b1.x,b1.y,b1.z,b1.w,
                       b2.x,b2.y,b2.z,b2.w, b3.x,b3.y,b3.z,b3.w};
      float Cv[DS_] = {c0.x,c0.y,c0.z,c0.w, c1.x,c1.y,c1.z,c1.w,
                       c2.x,c2.y,c2.z,c2.w, c3.x,c3.y,c3.z,c3.w};
      float dv = ysm[s][d];
      float xv = bf2f(gls[s][d]);
      float dvx = dv * xv;
      float pw[DS_];
      float p = exp2f(dv * a2_0);
      POW_TREE(p, pw);
      float y0 = Dv * xv, y1 = 0.f, y2 = 0.f, y3 = 0.f;
#pragma unroll
      for (int k = 0; k < 4; k++) {
        int n0 = k, n1_ = 4 + k, n2 = 8 + k, n3 = 12 + k;
        h[n0] = fmaf(pw[n0], h[n0], dvx * Bv[n0]);
        y0 = fmaf(h[n0], Cv[n0], y0);
        h[n1_] = fmaf(pw[n1_], h[n1_], dvx * Bv[n1_]);
        y1 = fmaf(h[n1_], Cv[n1_], y1);
        h[n2] = fmaf(pw[n2], h[n2], dvx * Bv[n2]);
        y2 = fmaf(h[n2], Cv[n2], y2);
        h[n3] = fmaf(pw[n3], h[n3], dvx * Bv[n3]);
        y3 = fmaf(h[n3], Cv[n3], y3);
      }
      ysm[s][d] = (y0 + y1) + (y2 + y3);
    }
  } else {
    float a2[DS_];
#pragma unroll
    for (int n = 0; n < DS_; n++)
      a2[n] = -__expf(A_logs[d * DS_ + n]) * 1.44269504f;
    for (int s = 0; s < CL_; s++) {
      float dv = ysm[s][d];
      float xv = bf2f(gls[s][d]);
      float dvx = dv * xv;
      float yy = Dv * xv;
      for (int n = 0; n < DS_; n++) {
        h[n] = fmaf(exp2f(dv * a2[n]), h[n], dvx * sBC[0][s][n]);
        yy = fmaf(h[n], sBC[1][s][n], yy);
      }
      ysm[s][d] = yy;
    }
  }
  __syncthreads();
  {
    int wid = d >> 6, lane = d & 63;
#pragma unroll
    for (int s6 = 0; s6 < CL_ / 4; s6++) {
      int s = wid * (CL_ / 4) + s6;
      float p0 = ysm[s][lane], p1 = ysm[s][lane + 64];
      float p2 = ysm[s][lane + 128], p3 = ysm[s][lane + 192];
      float s1 = (p0 + p1) + (p2 + p3);
      float s2 = (p0*p0 + p1*p1) + (p2*p2 + p3*p3);
#pragma unroll
      for (int off = 32; off >= 1; off >>= 1) {
        s1 += __shfl_xor(s1, off);
        s2 += __shfl_xor(s2, off);
      }
      if (lane == 0) {
        float mu = s1 / DI_;
        smu[s] = mu;
        srs[s] = rsqrtf(s2 / DI_ - mu * mu + 1e-5f);
      }
    }
  }
  __syncthreads();
  float lg = lng[d], lb = lnb[d];
#pragma unroll
  for (int s = 0; s < CL_; s++) {
    float v = (ysm[s][d] - smu[s]) * srs[s] * lg + lb;
    float zz = bf2f(zb[(base + s) * DI_ + d]);
    float sg = zz / (1.f + __expf(-zz));
    gls[s][d] = f2bf(v * sg);
  }
  __syncthreads();
  // ---- fused out_proj: (24x256) @ (256x128)^T via MFMA; 4 waves x (2 M-tiles x 2 N-tiles)
  {
    int wid = d >> 6, lane = d & 63;
    int colp = lane & 15, r4p = (lane >> 4) * 4;
    int k0 = (lane >> 4) * 8;
    f32x4 oacc[2][2];
#pragma unroll
    for (int mt = 0; mt < 2; mt++)
#pragma unroll
      for (int j = 0; j < 2; j++) oacc[mt][j] = (f32x4){0.f, 0.f, 0.f, 0.f};
#pragma unroll
    for (int ks = 0; ks < 8; ks++) {
      short8 a0 = *(const short8*)&gls[lane & 15][ks * 32 + k0];
      short8 a1 = *(const short8*)&gls[16 + (lane & 15)][ks * 32 + k0];
#pragma unroll
      for (int j = 0; j < 2; j++) {
        int nt = wid * 2 + j;
        short8 bfr = *(const short8*)(wop + (((ks * 8 + nt) * 64 + lane) << 3));
        oacc[0][j] = __builtin_amdgcn_mfma_f32_16x16x32_bf16(a0, bfr, oacc[0][j], 0, 0, 0);
        oacc[1][j] = __builtin_amdgcn_mfma_f32_16x16x32_bf16(a1, bfr, oacc[1][j], 0, 0, 0);
      }
    }
#pragma unroll
    for (int mt = 0; mt < 2; mt++)
#pragma unroll
      for (int j = 0; j < 2; j++) {
        int nt = wid * 2 + j;
#pragma unroll
        for (int q = 0; q < 4; q++) {
          int rl = mt * 16 + r4p + q;
          if (rl < CL_)
            out[(base + rl) * DM_ + nt * 16 + colp] = oacc[mt][j][q];
        }
      }
  }
}

extern "C" void kernel_launch(void* const* d_in, const int* in_sizes, int n_in,
                              void* d_out, int out_size, void* d_ws, size_t ws_size,
                              hipStream_t stream) {
  const float* x         = (const float*)d_in[0];
  const float* in_proj_w = (const float*)d_in[1];
  const float* conv_w    = (const float*)d_in[2];
  const float* conv_b    = (const float*)d_in[3];
  const float* x_proj_w  = (const float*)d_in[4];
  const float* dt_w      = (const float*)d_in[5];
  const float* dt_b      = (const float*)d_in[6];
  const float* A_logs    = (const float*)d_in[7];
  const float* Ds        = (const float*)d_in[8];
  const float* ln_g      = (const float*)d_in[9];
  const float* ln_b      = (const float*)d_in[10];
  const float* out_proj_w= (const float*)d_in[11];
  float* out = (float*)d_out;

  float* ws = (float*)d_ws;
  size_t n1 = (size_t)BL_ * DI_;
  // slot 0: xi bf16 -> S_buf bf16 (same u16 region; xi dead after conv)
  unsigned short* xi_bf = (unsigned short*)ws;
  unsigned short* S_buf = (unsigned short*)ws;
  // slot 1: z bf16 + xs bf16
  unsigned short* z_bf  = (unsigned short*)(ws + n1);
  unsigned short* xs_bf = z_bf + n1;
  // slot 3: delta bf16
  unsigned short* delta_bf = (unsigned short*)(ws + 3 * n1);
  float* Bsb    = ws + 4 * n1;
  float* Csb    = Bsb + (size_t)BL_ * DS_;
  unsigned short* hin_loc = (unsigned short*)(Csb + (size_t)BL_ * DS_);   // bf16, 6.3 MB
  float* sumD   = (float*)(hin_loc + (size_t)B_ * C_ * DI_ * DS_);
  float* HgS    = sumD + (size_t)B_ * C_ * DI_;
  float* gsd    = HgS + (size_t)B_ * G_ * DI_ * DS_;
  unsigned short* wallp = (unsigned short*)(gsd + (size_t)B_ * G_ * DI_);
  unsigned short* w2p   = wallp + 288 * DI_;
  unsigned short* wop   = w2p + 512 * DM_;
  unsigned short* x_bf  = hin_loc;   // scratch; dead before scan2a writes hin_loc

  k_wprep<<<672 + (BL_ * DM_) / 2048, 256, 0, stream>>>(x_proj_w, dt_w, in_proj_w, out_proj_w, x,
                                                        wallp, w2p, wop, x_bf);
  k_in_mfma<<<dim3(BL_ / 64, 2), 256, 0, stream>>>(x_bf, w2p, xi_bf, z_bf);
  k_conv<<<dim3(W_ / 32, H_, B_), 256, 0, stream>>>(xi_bf, conv_w, conv_b, xs_bf);
  k_xmfma<<<dim3(BL_ / 64, 3), 256, 0, stream>>>(xs_bf, wallp, dt_b, delta_bf, Bsb, Csb);
  k_scan1<<<dim3(C_, B_), 256, 0, stream>>>(delta_bf, xs_bf, Bsb, A_logs, S_buf, sumD);
  k_scan2a<<<(B_ * G_ * DI_ * DS_) / 256, 256, 0, stream>>>(S_buf, sumD, A_logs, hin_loc, HgS, gsd);
  k_scan2b<<<(B_ * DI_ * DS_) / 256, 256, 0, stream>>>(HgS, gsd, A_logs);
  k_scan3<<<dim3(C_, B_), 256, 0, stream>>>(delta_bf, xs_bf, Bsb, Csb, A_logs, Ds, hin_loc, HgS, sumD,
                                            z_bf, ln_g, ln_b, wop, out);
}

// Round 16
// 105.344 us; speedup vs baseline: 1.3761x; 1.0635x over previous
//
#include <hip/hip_runtime.h>
#include <math.h>

#define B_ 2
#define H_ 96
#define W_ 96
#define L_ (H_*W_)        // 9216
#define BL_ (B_*L_)       // 18432
#define DM_ 128
#define DI_ 256
#define DS_ 16
#define DR_ 8
#define C_ 384            // chunks per sequence
#define CL_ (L_/C_)       // 24 steps per chunk
#define G_ 16             // chunk groups per sequence
#define GC_ (C_/G_)       // 24 chunks per group
#define GP_ 264           // padded LDS tile row stride (ushorts): 528B -> 4-bank rotation

typedef __attribute__((ext_vector_type(8))) short short8;   // 8 bf16 in 4 VGPRs
typedef __attribute__((ext_vector_type(4))) float f32x4;    // MFMA accumulator

static __device__ __forceinline__ unsigned short f2bf(float f) {
  unsigned int u = __float_as_uint(f);
  unsigned int r = (u + 0x7fffu + ((u >> 16) & 1u)) >> 16;  // RNE
  return (unsigned short)r;
}
static __device__ __forceinline__ float bf2f(unsigned short u) {
  return __uint_as_float(((unsigned int)u) << 16);
}

// p^(k+1) for k=0..15 via binary tree (depth 4, 15 muls)
#define POW_TREE(p, pw) \
  pw[0]=(p); pw[1]=pw[0]*pw[0]; pw[2]=pw[1]*pw[0]; pw[3]=pw[1]*pw[1]; \
  pw[4]=pw[3]*pw[0]; pw[5]=pw[3]*pw[1]; pw[6]=pw[3]*pw[2]; pw[7]=pw[3]*pw[3]; \
  pw[8]=pw[7]*pw[0]; pw[9]=pw[7]*pw[1]; pw[10]=pw[7]*pw[2]; pw[11]=pw[7]*pw[3]; \
  pw[12]=pw[7]*pw[4]; pw[13]=pw[7]*pw[5]; pw[14]=pw[7]*pw[6]; pw[15]=pw[7]*pw[7];

// ---------------- Weight prep (packed bf16 fragment panels) + x->bf16 ----------------
__global__ __launch_bounds__(256) void k_wprep(const float* __restrict__ xpw,
                                               const float* __restrict__ dtw,
                                               const float* __restrict__ ipw,
                                               const float* __restrict__ opw,
                                               const float* __restrict__ x,
                                               unsigned short* __restrict__ wallp,
                                               unsigned short* __restrict__ w2p,
                                               unsigned short* __restrict__ wop,
                                               unsigned short* __restrict__ xbf) {
  int bid = blockIdx.x, tid = threadIdx.x;
  if (bid < 288) {                       // Wall: 288 x 256 (K=256, 8 ks, 18 tiles)
    int n = bid, k = tid;
    float v;
    if (n < 256) {
      float s = 0.f;
#pragma unroll
      for (int r = 0; r < DR_; r++) s += xpw[r * DI_ + k] * dtw[n * DR_ + r];
      v = s;
    } else {
      v = xpw[(n - 248) * DI_ + k];      // B rows (8..23) and C rows (24..39)
    }
    int t = n >> 4, col = n & 15, ks = k >> 5, kk = k & 31;
    int lane = (kk >> 3) * 16 + col, i = kk & 7;
    wallp[(((ks * 18 + t) * 64 + lane) << 3) + i] = f2bf(v);
  } else if (bid < 544) {                // in_proj: 512 x 128 (K=128, 4 ks, 32 tiles)
    int n = (bid - 288) * 2 + (tid >> 7), k = tid & 127;
    int t = n >> 4, col = n & 15, ks = k >> 5, kk = k & 31;
    int lane = (kk >> 3) * 16 + col, i = kk & 7;
    w2p[(((ks * 32 + t) * 64 + lane) << 3) + i] = f2bf(ipw[n * DM_ + k]);
  } else if (bid < 672) {                // out_proj: 128 x 256 (K=256, 8 ks, 8 tiles)
    int n = bid - 544, k = tid;
    int t = n >> 4, col = n & 15, ks = k >> 5, kk = k & 31;
    int lane = (kk >> 3) * 16 + col, i = kk & 7;
    wop[(((ks * 8 + t) * 64 + lane) << 3) + i] = f2bf(opw[n * DI_ + k]);
  } else {                               // x -> bf16
    int i = ((bid - 672) * 256 + tid) * 8;
    float4 f0 = *(const float4*)(x + i);
    float4 f1 = *(const float4*)(x + i + 4);
    short8 o;
    o[0]=(short)f2bf(f0.x); o[1]=(short)f2bf(f0.y); o[2]=(short)f2bf(f0.z); o[3]=(short)f2bf(f0.w);
    o[4]=(short)f2bf(f1.x); o[5]=(short)f2bf(f1.y); o[6]=(short)f2bf(f1.z); o[7]=(short)f2bf(f1.w);
    *(short8*)(xbf + i) = o;
  }
}

// ---------------- in_proj MFMA: (BL,128)x(128,512) -> xi bf16 | z bf16, col-split x2 ----------------
__global__ __launch_bounds__(256) void k_in_mfma(const unsigned short* __restrict__ xbf,
                                                 const unsigned short* __restrict__ w2p,
                                                 unsigned short* __restrict__ xi_bf,
                                                 unsigned short* __restrict__ zb) {
  int wid = threadIdx.x >> 6, lane = threadIdx.x & 63;
  int m0 = blockIdx.x * 64 + wid * 16;
  int t0 = blockIdx.y * 16;
  int row = m0 + (lane & 15);
  int col = lane & 15, r4 = (lane >> 4) * 4;
  f32x4 acc[16];
#pragma unroll
  for (int j = 0; j < 16; j++) acc[j] = (f32x4){0.f, 0.f, 0.f, 0.f};
#pragma unroll
  for (int ks = 0; ks < 4; ks++) {
    short8 a = *(const short8*)(xbf + (size_t)row * DM_ + ks * 32 + (lane >> 4) * 8);
#pragma unroll
    for (int j = 0; j < 16; j++) {
      short8 b = *(const short8*)(w2p + (((ks * 32 + t0 + j) * 64 + lane) << 3));
      acc[j] = __builtin_amdgcn_mfma_f32_16x16x32_bf16(a, b, acc[j], 0, 0, 0);
    }
  }
#pragma unroll
  for (int j = 0; j < 16; j++) {
    int tg = t0 + j;
    if (tg < 16) {
#pragma unroll
      for (int q = 0; q < 4; q++)
        xi_bf[(size_t)(m0 + r4 + q) * DI_ + tg * 16 + col] = f2bf(acc[j][q]);
    } else {
#pragma unroll
      for (int q = 0; q < 4; q++)
        zb[(size_t)(m0 + r4 + q) * DI_ + (tg - 16) * 16 + col] = f2bf(acc[j][q]);
    }
  }
}

// ---------------- fused: depthwise conv + SiLU -> xs (global + LDS), then x-side MFMA ----------------
// Block = 32 consecutive locations (one h row, 32 w's) x 256 channels.
__global__ __launch_bounds__(256, 2) void k_conv_x(const unsigned short* __restrict__ xi_bf,
                                                   const float* __restrict__ cw,
                                                   const float* __restrict__ cb,
                                                   const unsigned short* __restrict__ wallp,
                                                   const float* __restrict__ dtb,
                                                   unsigned short* __restrict__ xs_bf,
                                                   unsigned short* __restrict__ delta_bf,
                                                   float* __restrict__ Bsb,
                                                   float* __restrict__ Csb) {
  int wt = blockIdx.x;        // 0..2 (32-wide tiles)
  int h  = blockIdx.y;        // 0..95
  int b  = blockIdx.z;        // 0..1
  int t  = threadIdx.x;
  __shared__ unsigned short xls[32][GP_];   // xs tile, padded stride
  {
    int wp = t >> 7;            // which 16-wide half
    int cp = t & 127;           // channel pair
    int d0 = cp * 2;
    int w0 = wt * 32 + wp * 16;
    float wgtA[9], wgtB[9];
#pragma unroll
    for (int k = 0; k < 9; k++) { wgtA[k] = cw[d0 * 9 + k]; wgtB[k] = cw[(d0 + 1) * 9 + k]; }
    float biasA = cb[d0], biasB = cb[d0 + 1];

    float vA[3][18], vB[3][18];
#pragma unroll
    for (int r = 0; r < 3; r++) {
      int hh = h - 1 + r;
      bool rok = (hh >= 0) & (hh < H_);
      const unsigned int* rowp = (const unsigned int*)(xi_bf + ((size_t)(b * H_ + hh) * W_) * DI_) + cp;
#pragma unroll
      for (int j = 0; j < 18; j++) {
        int ww = w0 - 1 + j;
        bool ok = rok & (ww >= 0) & (ww < W_);
        unsigned int u = ok ? rowp[(size_t)ww * (DI_ / 2)] : 0u;
        vA[r][j] = bf2f((unsigned short)(u & 0xffffu));
        vB[r][j] = bf2f((unsigned short)(u >> 16));
      }
    }
#pragma unroll
    for (int j = 0; j < 16; j++) {
      float accA = biasA, accB = biasB;
#pragma unroll
      for (int r = 0; r < 3; r++)
#pragma unroll
        for (int q = 0; q < 3; q++) {
          accA = fmaf(vA[r][j + q], wgtA[r * 3 + q], accA);
          accB = fmaf(vB[r][j + q], wgtB[r * 3 + q], accB);
        }
      float oA = accA / (1.f + __expf(-accA));
      float oB = accB / (1.f + __expf(-accB));
      size_t bl = (size_t)(b * H_ + h) * W_ + w0 + j;
      unsigned int o = (unsigned int)f2bf(oA) | ((unsigned int)f2bf(oB) << 16);
      *(unsigned int*)(xs_bf + bl * DI_ + d0) = o;
      *(unsigned int*)&xls[wp * 16 + j][d0] = o;
    }
  }
  __syncthreads();
  // ---- x-side MFMA for these 32 rows: (32x256) @ Wall^T (288 cols) ----
  {
    int wv = t >> 6, lane = t & 63;
    int col = lane & 15, r4 = (lane >> 4) * 4;
    int k0 = (lane >> 4) * 8;
    size_t baseL = (size_t)(b * H_ + h) * W_ + wt * 32;
    for (int tt = wv; tt < 18; tt += 4) {
      f32x4 acc0 = (f32x4){0.f, 0.f, 0.f, 0.f};
      f32x4 acc1 = (f32x4){0.f, 0.f, 0.f, 0.f};
#pragma unroll
      for (int ks = 0; ks < 8; ks++) {
        short8 a0 = *(const short8*)&xls[lane & 15][ks * 32 + k0];
        short8 a1 = *(const short8*)&xls[16 + (lane & 15)][ks * 32 + k0];
        short8 bfr = *(const short8*)(wallp + (((ks * 18 + tt) * 64 + lane) << 3));
        acc0 = __builtin_amdgcn_mfma_f32_16x16x32_bf16(a0, bfr, acc0, 0, 0, 0);
        acc1 = __builtin_amdgcn_mfma_f32_16x16x32_bf16(a1, bfr, acc1, 0, 0, 0);
      }
      if (tt < 16) {
        float bias = dtb[tt * 16 + col];
#pragma unroll
        for (int q = 0; q < 4; q++) {
          float v0 = acc0[q] + bias;
          float v1 = acc1[q] + bias;
          float sp0 = (v0 > 20.f) ? v0 : log1pf(__expf(v0));
          float sp1 = (v1 > 20.f) ? v1 : log1pf(__expf(v1));
          delta_bf[(baseL + r4 + q) * DI_ + tt * 16 + col] = f2bf(sp0);
          delta_bf[(baseL + 16 + r4 + q) * DI_ + tt * 16 + col] = f2bf(sp1);
        }
      } else if (tt == 16) {
#pragma unroll
        for (int q = 0; q < 4; q++) {
          Bsb[(baseL + r4 + q) * DS_ + col] = acc0[q];
          Bsb[(baseL + 16 + r4 + q) * DS_ + col] = acc1[q];
        }
      } else {
#pragma unroll
        for (int q = 0; q < 4; q++) {
          Csb[(baseL + r4 + q) * DS_ + col] = acc0[q];
          Csb[(baseL + 16 + r4 + q) * DS_ + col] = acc1[q];
        }
      }
    }
  }
}

// ---------------- Scan pass 1: LDS-staged chunk scan, power-chain dA; S stored bf16 ----------------
__global__ __launch_bounds__(256, 3) void k_scan1(const unsigned short* __restrict__ delta_bf,
                                                  const unsigned short* __restrict__ xs_bf,
                                                  const float* __restrict__ Bsb,
                                                  const float* __restrict__ A_logs,
                                                  unsigned short* __restrict__ S_buf,
                                                  float* __restrict__ sumD_buf) {
  int c = blockIdx.x, b = blockIdx.y;
  int d = threadIdx.x;
  __shared__ float sD[CL_][DI_];            // 24 KB (f32, converted at stage)
  __shared__ unsigned short sX[CL_][DI_];   // 12 KB
  __shared__ float sB[CL_][DS_];            // 1.5 KB
  size_t base = (size_t)b * L_ + (size_t)c * CL_;
  for (int i = d; i < CL_ * DS_; i += 256)
    sB[i >> 4][i & 15] = Bsb[base * DS_ + i];
  for (int i = d; i < CL_ * DI_ / 8; i += 256) {
    short8 v = ((const short8*)(delta_bf + base * DI_))[i];
    float* p = &sD[0][0] + i * 8;
    p[0]=bf2f((unsigned short)v[0]); p[1]=bf2f((unsigned short)v[1]);
    p[2]=bf2f((unsigned short)v[2]); p[3]=bf2f((unsigned short)v[3]);
    p[4]=bf2f((unsigned short)v[4]); p[5]=bf2f((unsigned short)v[5]);
    p[6]=bf2f((unsigned short)v[6]); p[7]=bf2f((unsigned short)v[7]);
  }
  for (int i = d; i < CL_ * DI_ / 8; i += 256)
    ((short8*)sX)[i] = ((const short8*)(xs_bf + base * DI_))[i];

  float a2_0 = -__expf(A_logs[d * DS_]) * 1.44269504f;
  bool fast = true;
#pragma unroll
  for (int n = 1; n < DS_; n++) {
    float a2n = -__expf(A_logs[d * DS_ + n]) * 1.44269504f;
    fast &= fabsf(a2n - (float)(n + 1) * a2_0) <= 1e-4f * fabsf(a2n);
  }
  __syncthreads();
  float h[DS_];
#pragma unroll
  for (int n = 0; n < DS_; n++) h[n] = 0.f;
  float sum = 0.f;
  if (fast) {
#pragma unroll
    for (int s = 0; s < CL_; s++) {
      float4 b0 = *(const float4*)&sB[s][0];
      float4 b1 = *(const float4*)&sB[s][4];
      float4 b2 = *(const float4*)&sB[s][8];
      float4 b3 = *(const float4*)&sB[s][12];
      float Bv[DS_] = {b0.x,b0.y,b0.z,b0.w, b1.x,b1.y,b1.z,b1.w,
                       b2.x,b2.y,b2.z,b2.w, b3.x,b3.y,b3.z,b3.w};
      float dv = sD[s][d];
      float dvx = dv * bf2f(sX[s][d]);
      sum += dv;
      float pw[DS_];
      float p = exp2f(dv * a2_0);
      POW_TREE(p, pw);
#pragma unroll
      for (int n = 0; n < DS_; n++)
        h[n] = fmaf(pw[n], h[n], dvx * Bv[n]);
    }
  } else {
    float a2[DS_];
#pragma unroll
    for (int n = 0; n < DS_; n++)
      a2[n] = -__expf(A_logs[d * DS_ + n]) * 1.44269504f;
    for (int s = 0; s < CL_; s++) {
      float dv = sD[s][d];
      float dvx = dv * bf2f(sX[s][d]);
      sum += dv;
      for (int n = 0; n < DS_; n++)
        h[n] = fmaf(exp2f(dv * a2[n]), h[n], dvx * sB[s][n]);
    }
  }
  size_t o = ((size_t)(b * C_ + c) * DI_ + d) * DS_;
  short8 s0, s1;
#pragma unroll
  for (int q = 0; q < 8; q++) s0[q] = (short)f2bf(h[q]);
#pragma unroll
  for (int q = 0; q < 8; q++) s1[q] = (short)f2bf(h[8 + q]);
  *(short8*)(S_buf + o) = s0;
  *(short8*)(S_buf + o + 8) = s1;
  sumD_buf[(size_t)(b * C_ + c) * DI_ + d] = sum;
}

// ---------------- Scan pass 2a: group-local chunk prefix (bf16 S in, bf16 hin out) ----------------
__global__ __launch_bounds__(256) void k_scan2a(const unsigned short* __restrict__ S_buf,
                                                float* __restrict__ sumD_csd,
                                                const float* __restrict__ A_logs,
                                                unsigned short* __restrict__ hin_loc,
                                                float* __restrict__ HgS,
                                                float* __restrict__ gsd) {
  int t = blockIdx.x * 256 + threadIdx.x;   // 0 .. B*G*DI*DS-1
  int b = t >> 16;
  int g = (t >> 12) & 15;
  int d = (t >> 4) & 255;
  int n = t & 15;
  float a2 = -__expf(A_logs[d * DS_ + n]) * 1.44269504f;
  float h = 0.f, csd = 0.f;
  int c0 = b * C_ + g * GC_;
  const size_t stride = (size_t)DI_ * DS_;
  size_t o  = ((size_t)c0 * DI_ + d) * DS_ + n;
  size_t od = (size_t)c0 * DI_ + d;
  float S  = bf2f(S_buf[o]);
  float sd = sumD_csd[od];
#pragma unroll
  for (int j = 0; j < GC_; j++) {
    float Sn = 0.f, sdn = 0.f;
    if (j + 1 < GC_) {
      Sn  = bf2f(S_buf[o + stride]);
      sdn = sumD_csd[od + DI_];
    }
    hin_loc[o] = f2bf(h);
    if (n == 0) sumD_csd[od] = csd;
    csd += sd;
    h = fmaf(exp2f(a2 * sd), h, S);
    S = Sn; sd = sdn;
    o += stride; od += DI_;
  }
  size_t og = ((size_t)(b * G_ + g) * DI_ + d) * DS_ + n;
  HgS[og] = h;
  if (n == 0) gsd[(size_t)(b * G_ + g) * DI_ + d] = csd;
}

// ---------------- Scan pass 2b: combine group summaries ----------------
__global__ __launch_bounds__(256) void k_scan2b(float* __restrict__ HgS_Hpre,
                                                const float* __restrict__ gsd,
                                                const float* __restrict__ A_logs) {
  int t = blockIdx.x * 256 + threadIdx.x;   // 0 .. 8191
  int b = t >> 12;
  int d = (t >> 4) & 255;
  int n = t & 15;
  float a2 = -__expf(A_logs[d * DS_ + n]) * 1.44269504f;
  float h = 0.f;
#pragma unroll
  for (int g = 0; g < G_; g++) {
    size_t o = ((size_t)(b * G_ + g) * DI_ + d) * DS_ + n;
    float Hg = HgS_Hpre[o];
    float sd = gsd[(size_t)(b * G_ + g) * DI_ + d];
    HgS_Hpre[o] = h;
    h = fmaf(exp2f(a2 * sd), h, Hg);
  }
}

// ---------------- Scan pass 3 + LN + SiLU(z) gate + fused out_proj MFMA -> out ----------------
__global__ __launch_bounds__(256, 3) void k_scan3(const unsigned short* __restrict__ delta_bf,
                                                   const unsigned short* __restrict__ xs_bf,
                                                   const float* __restrict__ Bsb,
                                                   const float* __restrict__ Csb,
                                                   const float* __restrict__ A_logs,
                                                   const float* __restrict__ Ds,
                                                   const unsigned short* __restrict__ hin_loc,
                                                   const float* __restrict__ Hpre,
                                                   const float* __restrict__ csd,
                                                   const unsigned short* __restrict__ zb,
                                                   const float* __restrict__ lng,
                                                   const float* __restrict__ lnb,
                                                   const unsigned short* __restrict__ wop,
                                                   float* __restrict__ out) {
  int c = blockIdx.x, b = blockIdx.y;
  int d = threadIdx.x;
  int grp = c / GC_;
  __shared__ float ysm[CL_][DI_];           // delta stage -> y
  __shared__ unsigned short gls[32][GP_];   // xs stage -> g tile
  __shared__ float sBC[2][CL_][DS_];
  __shared__ float smu[CL_], srs[CL_];
  size_t base = (size_t)b * L_ + (size_t)c * CL_;
  for (int i = d; i < CL_ * DS_; i += 256) {
    sBC[0][i >> 4][i & 15] = Bsb[base * DS_ + i];
    sBC[1][i >> 4][i & 15] = Csb[base * DS_ + i];
  }
  for (int i = d; i < CL_ * DI_ / 8; i += 256) {
    short8 v = ((const short8*)(delta_bf + base * DI_))[i];
    float* p = &ysm[0][0] + i * 8;
    p[0]=bf2f((unsigned short)v[0]); p[1]=bf2f((unsigned short)v[1]);
    p[2]=bf2f((unsigned short)v[2]); p[3]=bf2f((unsigned short)v[3]);
    p[4]=bf2f((unsigned short)v[4]); p[5]=bf2f((unsigned short)v[5]);
    p[6]=bf2f((unsigned short)v[6]); p[7]=bf2f((unsigned short)v[7]);
  }
  for (int i = d; i < CL_ * 32; i += 256) {
    int row = i >> 5, c8 = i & 31;
    *(short8*)&gls[row][c8 * 8] = ((const short8*)(xs_bf + base * DI_))[i];
  }
  float a2_0 = -__expf(A_logs[d * DS_]) * 1.44269504f;
  bool fast = true;
#pragma unroll
  for (int n = 1; n < DS_; n++) {
    float a2n = -__expf(A_logs[d * DS_ + n]) * 1.44269504f;
    fast &= fabsf(a2n - (float)(n + 1) * a2_0) <= 1e-4f * fabsf(a2n);
  }
  float Dv = Ds[d];
  size_t ho = ((size_t)(b * C_ + c) * DI_ + d) * DS_;
  size_t go = ((size_t)(b * G_ + grp) * DI_ + d) * DS_;
  float cs = csd[(size_t)(b * C_ + c) * DI_ + d];
  float h[DS_];
  {
    short8 t0 = *(const short8*)(hin_loc + ho);
    short8 t1 = *(const short8*)(hin_loc + ho + 8);
    float tl[DS_];
#pragma unroll
    for (int q = 0; q < 8; q++) tl[q] = bf2f((unsigned short)t0[q]);
#pragma unroll
    for (int q = 0; q < 8; q++) tl[8 + q] = bf2f((unsigned short)t1[q]);
    if (fast) {
      float pw[DS_];
      float p = exp2f(cs * a2_0);
      POW_TREE(p, pw);
#pragma unroll
      for (int q = 0; q < 4; q++) {
        float4 tp = *(const float4*)(Hpre + go + 4 * q);
        h[4*q+0] = fmaf(pw[4*q+0], tp.x, tl[4*q+0]);
        h[4*q+1] = fmaf(pw[4*q+1], tp.y, tl[4*q+1]);
        h[4*q+2] = fmaf(pw[4*q+2], tp.z, tl[4*q+2]);
        h[4*q+3] = fmaf(pw[4*q+3], tp.w, tl[4*q+3]);
      }
    } else {
#pragma unroll
      for (int n = 0; n < DS_; n++) {
        float a2n = -__expf(A_logs[d * DS_ + n]) * 1.44269504f;
        h[n] = fmaf(exp2f(cs * a2n), Hpre[go + n], tl[n]);
      }
    }
  }
  __syncthreads();
  if (fast) {
#pragma unroll
    for (int s = 0; s < CL_; s++) {
      float4 b0 = *(const float4*)&sBC[0][s][0];
      float4 b1 = *(const float4*)&sBC[0][s][4];
      float4 b2 = *(const float4*)&sBC[0][s][8];
      float4 b3 = *(const float4*)&sBC[0][s][12];
      float4 c0 = *(const float4*)&sBC[1][s][0];
      float4 c1 = *(const float4*)&sBC[1][s][4];
      float4 c2 = *(const float4*)&sBC[1][s][8];
      float4 c3 = *(const float4*)&sBC[1][s][12];
      float Bv[DS_] = {b0.x,b0.y,b0.z,b0.w, b1.x,b1.y,b1.z,b1.w,
                       b2.x,b2.y,b2.z,b2.w, b3.x,b3.y,b3.z,b3.w};
      float Cv[DS_] = {c0.x,c0.y,c0.z,c0.w, c1.x,c1.y,c1.z,c1.w,
                       c2.x,c2.y,c2.z,c2.w, c3.x,c3.y,c3.z,c3.w};
      float dv = ysm[s][d];
      float xv = bf2f(gls[s][d]);
      float dvx = dv * xv;
      float pw[DS_];
      float p = exp2f(dv * a2_0);
      POW_TREE(p, pw);
      float y0 = Dv * xv, y1 = 0.f, y2 = 0.f, y3 = 0.f;
#pragma unroll
      for (int k = 0; k < 4; k++) {
        int n0 = k, n1_ = 4 + k, n2 = 8 + k, n3 = 12 + k;
        h[n0] = fmaf(pw[n0], h[n0], dvx * Bv[n0]);
        y0 = fmaf(h[n0], Cv[n0], y0);
        h[n1_] = fmaf(pw[n1_], h[n1_], dvx * Bv[n1_]);
        y1 = fmaf(h[n1_], Cv[n1_], y1);
        h[n2] = fmaf(pw[n2], h[n2], dvx * Bv[n2]);
        y2 = fmaf(h[n2], Cv[n2], y2);
        h[n3] = fmaf(pw[n3], h[n3], dvx * Bv[n3]);
        y3 = fmaf(h[n3], Cv[n3], y3);
      }
      ysm[s][d] = (y0 + y1) + (y2 + y3);
    }
  } else {
    float a2[DS_];
#pragma unroll
    for (int n = 0; n < DS_; n++)
      a2[n] = -__expf(A_logs[d * DS_ + n]) * 1.44269504f;
    for (int s = 0; s < CL_; s++) {
      float dv = ysm[s][d];
      float xv = bf2f(gls[s][d]);
      float dvx = dv * xv;
      float yy = Dv * xv;
      for (int n = 0; n < DS_; n++) {
        h[n] = fmaf(exp2f(dv * a2[n]), h[n], dvx * sBC[0][s][n]);
        yy = fmaf(h[n], sBC[1][s][n], yy);
      }
      ysm[s][d] = yy;
    }
  }
  __syncthreads();
  {
    int wid = d >> 6, lane = d & 63;
#pragma unroll
    for (int s6 = 0; s6 < CL_ / 4; s6++) {
      int s = wid * (CL_ / 4) + s6;
      float p0 = ysm[s][lane], p1 = ysm[s][lane + 64];
      float p2 = ysm[s][lane + 128], p3 = ysm[s][lane + 192];
      float s1 = (p0 + p1) + (p2 + p3);
      float s2 = (p0*p0 + p1*p1) + (p2*p2 + p3*p3);
#pragma unroll
      for (int off = 32; off >= 1; off >>= 1) {
        s1 += __shfl_xor(s1, off);
        s2 += __shfl_xor(s2, off);
      }
      if (lane == 0) {
        float mu = s1 / DI_;
        smu[s] = mu;
        srs[s] = rsqrtf(s2 / DI_ - mu * mu + 1e-5f);
      }
    }
  }
  __syncthreads();
  float lg = lng[d], lb = lnb[d];
#pragma unroll
  for (int s = 0; s < CL_; s++) {
    float v = (ysm[s][d] - smu[s]) * srs[s] * lg + lb;
    float zz = bf2f(zb[(base + s) * DI_ + d]);
    float sg = zz / (1.f + __expf(-zz));
    gls[s][d] = f2bf(v * sg);
  }
  __syncthreads();
  // ---- fused out_proj: (24x256) @ (256x128)^T via MFMA; 4 waves x (2 M-tiles x 2 N-tiles)
  {
    int wid = d >> 6, lane = d & 63;
    int colp = lane & 15, r4p = (lane >> 4) * 4;
    int k0 = (lane >> 4) * 8;
    f32x4 oacc[2][2];
#pragma unroll
    for (int mt = 0; mt < 2; mt++)
#pragma unroll
      for (int j = 0; j < 2; j++) oacc[mt][j] = (f32x4){0.f, 0.f, 0.f, 0.f};
#pragma unroll
    for (int ks = 0; ks < 8; ks++) {
      short8 a0 = *(const short8*)&gls[lane & 15][ks * 32 + k0];
      short8 a1 = *(const short8*)&gls[16 + (lane & 15)][ks * 32 + k0];
#pragma unroll
      for (int j = 0; j < 2; j++) {
        int nt = wid * 2 + j;
        short8 bfr = *(const short8*)(wop + (((ks * 8 + nt) * 64 + lane) << 3));
        oacc[0][j] = __builtin_amdgcn_mfma_f32_16x16x32_bf16(a0, bfr, oacc[0][j], 0, 0, 0);
        oacc[1][j] = __builtin_amdgcn_mfma_f32_16x16x32_bf16(a1, bfr, oacc[1][j], 0, 0, 0);
      }
    }
#pragma unroll
    for (int mt = 0; mt < 2; mt++)
#pragma unroll
      for (int j = 0; j < 2; j++) {
        int nt = wid * 2 + j;
#pragma unroll
        for (int q = 0; q < 4; q++) {
          int rl = mt * 16 + r4p + q;
          if (rl < CL_)
            out[(base + rl) * DM_ + nt * 16 + colp] = oacc[mt][j][q];
        }
      }
  }
}

extern "C" void kernel_launch(void* const* d_in, const int* in_sizes, int n_in,
                              void* d_out, int out_size, void* d_ws, size_t ws_size,
                              hipStream_t stream) {
  const float* x         = (const float*)d_in[0];
  const float* in_proj_w = (const float*)d_in[1];
  const float* conv_w    = (const float*)d_in[2];
  const float* conv_b    = (const float*)d_in[3];
  const float* x_proj_w  = (const float*)d_in[4];
  const float* dt_w      = (const float*)d_in[5];
  const float* dt_b      = (const float*)d_in[6];
  const float* A_logs    = (const float*)d_in[7];
  const float* Ds        = (const float*)d_in[8];
  const float* ln_g      = (const float*)d_in[9];
  const float* ln_b      = (const float*)d_in[10];
  const float* out_proj_w= (const float*)d_in[11];
  float* out = (float*)d_out;

  float* ws = (float*)d_ws;
  size_t n1 = (size_t)BL_ * DI_;
  // slot 0: xi bf16 -> S_buf bf16 (same u16 region; xi dead after conv_x)
  unsigned short* xi_bf = (unsigned short*)ws;
  unsigned short* S_buf = (unsigned short*)ws;
  // slot 1: z bf16 + xs bf16
  unsigned short* z_bf  = (unsigned short*)(ws + n1);
  unsigned short* xs_bf = z_bf + n1;
  // slot 3: delta bf16
  unsigned short* delta_bf = (unsigned short*)(ws + 3 * n1);
  float* Bsb    = ws + 4 * n1;
  float* Csb    = Bsb + (size_t)BL_ * DS_;
  unsigned short* hin_loc = (unsigned short*)(Csb + (size_t)BL_ * DS_);   // bf16, 6.3 MB
  float* sumD   = (float*)(hin_loc + (size_t)B_ * C_ * DI_ * DS_);
  float* HgS    = sumD + (size_t)B_ * C_ * DI_;
  float* gsd    = HgS + (size_t)B_ * G_ * DI_ * DS_;
  unsigned short* wallp = (unsigned short*)(gsd + (size_t)B_ * G_ * DI_);
  unsigned short* w2p   = wallp + 288 * DI_;
  unsigned short* wop   = w2p + 512 * DM_;
  unsigned short* x_bf  = hin_loc;   // scratch; dead before scan2a writes hin_loc

  k_wprep<<<672 + (BL_ * DM_) / 2048, 256, 0, stream>>>(x_proj_w, dt_w, in_proj_w, out_proj_w, x,
                                                        wallp, w2p, wop, x_bf);
  k_in_mfma<<<dim3(BL_ / 64, 2), 256, 0, stream>>>(x_bf, w2p, xi_bf, z_bf);
  k_conv_x<<<dim3(W_ / 32, H_, B_), 256, 0, stream>>>(xi_bf, conv_w, conv_b, wallp, dt_b,
                                                      xs_bf, delta_bf, Bsb, Csb);
  k_scan1<<<dim3(C_, B_), 256, 0, stream>>>(delta_bf, xs_bf, Bsb, A_logs, S_buf, sumD);
  k_scan2a<<<(B_ * G_ * DI_ * DS_) / 256, 256, 0, stream>>>(S_buf, sumD, A_logs, hin_loc, HgS, gsd);
  k_scan2b<<<(B_ * DI_ * DS_) / 256, 256, 0, stream>>>(HgS, gsd, A_logs);
  k_scan3<<<dim3(C_, B_), 256, 0, stream>>>(delta_bf, xs_bf, Bsb, Csb, A_logs, Ds, hin_loc, HgS, sumD,
                                            z_bf, ln_g, ln_b, wop, out);
}